// Round 9
// baseline (67994.751 us; speedup 1.0000x reference)
//
#include <hip/hip_runtime.h>
#include <hip/hip_bf16.h>

#define SEQ_LEN 256
#define NB 64
#define NV 10000
#define ND 1024
#define NBLK 256

typedef unsigned int u32;
typedef unsigned short u16;

__device__ __forceinline__ float sigf(float z) { return 1.f / (1.f + expf(-z)); }

__device__ __forceinline__ float bflo(u32 u) {
  union { u32 i; float f; } v; v.i = u << 16; return v.f;
}
__device__ __forceinline__ float bfhi(u32 u) {
  union { u32 i; float f; } v; v.i = u & 0xffff0000u; return v.f;
}
__device__ __forceinline__ u16 f2bf(float f) {   // RNE
  u32 u = __float_as_uint(f);
  u32 r = u + 0x7FFFu + ((u >> 16) & 1u);
  return (u16)(r >> 16);
}

__device__ __forceinline__ float dot8_f32(const float* hv, const float* wp, float acc) {
  float4 w0 = *(const float4*)wp;
  float4 w1 = *(const float4*)(wp + 4);
  acc += hv[0] * w0.x; acc += hv[1] * w0.y; acc += hv[2] * w0.z; acc += hv[3] * w0.w;
  acc += hv[4] * w1.x; acc += hv[5] * w1.y; acc += hv[6] * w1.z; acc += hv[7] * w1.w;
  return acc;
}

// 8 bf16 weights from LDS (wave-uniform address -> broadcast, conflict-free)
__device__ __forceinline__ float dot8_w(const float* hv, const u16* wp, float acc) {
  uint4 wu = *(const uint4*)wp;
  acc = fmaf(hv[0], bflo(wu.x), acc); acc = fmaf(hv[1], bfhi(wu.x), acc);
  acc = fmaf(hv[2], bflo(wu.y), acc); acc = fmaf(hv[3], bfhi(wu.y), acc);
  acc = fmaf(hv[4], bflo(wu.z), acc); acc = fmaf(hv[5], bfhi(wu.z), acc);
  acc = fmaf(hv[6], bflo(wu.w), acc); acc = fmaf(hv[7], bfhi(wu.w), acc);
  return acc;
}

// ---- diagnostic flood (f32 out) ----
__global__ void floodk(float* out, float val, unsigned long long n) {
  unsigned long long i = (unsigned long long)blockIdx.x * 256 + threadIdx.x;
  if (i < n) out[i] = val;
}

// ---- init: transpose states to feature-major, zero barrier flags ----
__global__ void init_state(const float* __restrict__ h0, const float* __restrict__ c0,
                           float* __restrict__ hT, float* __restrict__ cT, u32* flags) {
  int i = blockIdx.x * 256 + threadIdx.x;   // 0..65535
  int k = i >> 6, b = i & 63;
  hT[i] = h0[b * ND + k];
  cT[i] = c0[b * ND + k];
  if (i < NBLK * 16) flags[i] = 0u;         // 64B-padded per-block flags
}

// ================= persistent fused sequence kernel =================
// grid 256 blocks x 512 thr (8 waves), 1 block/CU. Weights bf16 in LDS.
// Flag-array barrier: per-block release-store to own cacheline (parallel
// arrivals, no RMW serialization); cooperative all-flags poll (read-shared).

__device__ __forceinline__ void fbar(u32* flags, u32 want, u32* wok) {
  __syncthreads();
  const int tid = threadIdx.x;
  if (tid == 0) {
    __threadfence();
    __hip_atomic_store(flags + (size_t)blockIdx.x * 16, want,
                       __ATOMIC_RELEASE, __HIP_MEMORY_SCOPE_AGENT);
  }
  const int wv = tid >> 6;
  for (;;) {
    int ok = 1;
    if (tid < NBLK) {
      u32 f = __hip_atomic_load(flags + (size_t)tid * 16,
                                __ATOMIC_RELAXED, __HIP_MEMORY_SCOPE_AGENT);
      ok = (f >= want);
    }
    ok = __all(ok);
    if ((tid & 63) == 0) wok[wv] = (u32)ok;
    __syncthreads();
    u32 all8 = wok[0] & wok[1] & wok[2] & wok[3] &
               wok[4] & wok[5] & wok[6] & wok[7];
    __syncthreads();
    if (all8) break;
    __builtin_amdgcn_s_sleep(1);
  }
  __threadfence();
  __syncthreads();
}

// mog phase: out[c][b] = 2*sig(sum_k act[k][b]*W[c][k] + bias[c]) * mult
template<bool EMB>
__device__ __forceinline__ void mogP(
    const float* __restrict__ actT, const u16* Wl,
    const float* __restrict__ bias, const float* __restrict__ emb,
    const int* __restrict__ tok, const float* __restrict__ multT,
    float* __restrict__ outT, float* red)
{
  const int tid = threadIdx.x;
  const int wv = tid >> 6, lane = tid & 63;
  const int c0 = blockIdx.x * 4;
  const int kb = wv * 128;
  float acc[4] = {0.f, 0.f, 0.f, 0.f};
  const float* ap = actT + (size_t)kb * NB + lane;

  for (int k = 0; k < 128; k += 8) {
    float hv[8];
#pragma unroll
    for (int q = 0; q < 8; ++q) hv[q] = ap[(k + q) * NB];
#pragma unroll
    for (int c = 0; c < 4; ++c)
      acc[c] = dot8_w(hv, Wl + c * 1024 + kb + k, acc[c]);
  }
#pragma unroll
  for (int c = 0; c < 4; ++c) red[(wv * 16 + c) * 64 + lane] = acc[c];
  __syncthreads();

  if (tid < 256) {
    const int c = tid >> 6, b = tid & 63;
    float z = 0.f;
#pragma unroll
    for (int w = 0; w < 8; ++w) z += red[(w * 16 + c) * 64 + b];
    z += bias[c0 + c];
    float g = 2.f * sigf(z);
    float m = EMB ? emb[(size_t)tok[b] * ND + (c0 + c)]
                  : multT[(size_t)(c0 + c) * NB + b];
    outT[(size_t)(c0 + c) * NB + b] = g * m;
  }
}

// gates phase: block owns 4 hidden cols (16 gate rows, local row r = jj*4+g);
// waves 0-3 x-half, 4-7 h-half; weights bf16 LDS.
__device__ __forceinline__ void gatesP(
    const float* __restrict__ xT, const float* __restrict__ hT,
    const u16* wG,
    const float* __restrict__ bih, const float* __restrict__ bhh,
    float* __restrict__ cT, float* __restrict__ hOut, float* red)
{
  const int tid = threadIdx.x;
  const int wv = tid >> 6, lane = tid & 63;
  const int j0 = blockIdx.x * 4;
  const int half = wv >> 2, kq = wv & 3;
  const int kb = kq * 256;
  const float* ap = (half ? hT : xT) + (size_t)kb * NB + lane;
  const u16* Wb = wG + half * (16 * 1024);

  float acc[16];
#pragma unroll
  for (int i = 0; i < 16; ++i) acc[i] = 0.f;

  for (int k = 0; k < 256; k += 8) {
    float av[8];
#pragma unroll
    for (int q = 0; q < 8; ++q) av[q] = ap[(k + q) * NB];
#pragma unroll
    for (int r = 0; r < 16; ++r)
      acc[r] = dot8_w(av, Wb + r * 1024 + kb + k, acc[r]);
  }
#pragma unroll
  for (int i = 0; i < 16; ++i) red[(wv * 16 + i) * 64 + lane] = acc[i];
  __syncthreads();

  if (tid < 256) {
    const int jj = tid >> 6, b = tid & 63;
    const int j = j0 + jj;
    float pre[4];
#pragma unroll
    for (int g = 0; g < 4; ++g) {
      float s = 0.f;
#pragma unroll
      for (int w = 0; w < 8; ++w) s += red[(w * 16 + jj * 4 + g) * 64 + b];
      pre[g] = s + bih[g * ND + j] + bhh[g * ND + j];
    }
    float iv = sigf(pre[0]), fv = sigf(pre[1]);
    float gv = tanhf(pre[2]), ov = sigf(pre[3]);
    float cn = fv * cT[(size_t)j * NB + b] + iv * gv;
    float hn = ov * tanhf(cn);
    cT[(size_t)j * NB + b] = cn;
    hOut[(size_t)j * NB + b] = hn;
  }
}

__global__ __launch_bounds__(512) void seq_kernel(
    const int* __restrict__ tokens, const float* __restrict__ emb,
    const float* __restrict__ qw, const float* __restrict__ qb,
    const float* __restrict__ rw, const float* __restrict__ rb,
    const float* __restrict__ wih, const float* __restrict__ whh,
    const float* __restrict__ bih, const float* __restrict__ bhh,
    float* __restrict__ xA, float* __restrict__ xB,
    float* __restrict__ h1, float* __restrict__ h3,
    float* __restrict__ cS, float* __restrict__ hHist, u32* flags)
{
  __shared__ u16 wMog[4 * 4 * 1024];     // 32 KB: [mat][col][k]
  __shared__ u16 wG[2 * 16 * 1024];      // 64 KB: [mat][row r=jj*4+g][k]
  __shared__ float red[8 * 16 * 64];     // 32 KB
  __shared__ u32 wok[8];

  const int tid = threadIdx.x;
  const int c0 = blockIdx.x * 4;
  const size_t DH = (size_t)ND * ND;
  const size_t SB = (size_t)ND * NB;

  // ---- one-time LDS weight fill (f32 -> bf16 RNE) ----
  {
    const float* msrc[4] = {qw, rw, qw + DH, rw + DH};
#pragma unroll
    for (int m = 0; m < 4; ++m)
      for (int c = 0; c < 4; ++c) {
        const float* src = msrc[m] + (size_t)(c0 + c) * ND;
        u16* dst = wMog + (m * 4 + c) * 1024;
        for (int k = tid; k < ND; k += 512) dst[k] = f2bf(src[k]);
      }
#pragma unroll
    for (int m = 0; m < 2; ++m) {
      const float* W = m ? whh : wih;
      for (int r = 0; r < 16; ++r) {
        const float* src = W + ((size_t)(r & 3) * ND + c0 + (r >> 2)) * ND;
        u16* dst = wG + (m * 16 + r) * 1024;
        for (int k = tid; k < ND; k += 512) dst[k] = f2bf(src[k]);
      }
    }
  }
  __syncthreads();

  u32 want = 0;
  for (int t = 0; t < SEQ_LEN; ++t) {
    const int* tok = tokens + (size_t)t * NB;
    float* hc = hHist + (size_t)t * SB;
    float* hn = hc + SB;
    mogP<true >(hc, wMog + 0 * 4096, qb,      emb, tok, nullptr, xA, red);    fbar(flags, ++want, wok);
    mogP<false>(xA, wMog + 1 * 4096, rb,      nullptr, nullptr, hc, h1, red); fbar(flags, ++want, wok);
    mogP<false>(h1, wMog + 2 * 4096, qb + ND, nullptr, nullptr, xA, xB, red); fbar(flags, ++want, wok);
    mogP<false>(xB, wMog + 3 * 4096, rb + ND, nullptr, nullptr, h1, h3, red); fbar(flags, ++want, wok);
    gatesP(xB, h3, wG, bih, bhh, cS, hn, red);                                fbar(flags, ++want, wok);
  }
}

// ================= fallback multi-launch kernels (proven) =================

template<bool EMB>
__global__ __launch_bounds__(256) void mog_phase(
    const float* __restrict__ actT, const float* __restrict__ W,
    const float* __restrict__ bias, const float* __restrict__ multT,
    const float* __restrict__ emb, const int* __restrict__ tok,
    float* __restrict__ outT)
{
  const int tid = threadIdx.x;
  const int wv = tid >> 6;
  const int lane = tid & 63;
  const int c0 = blockIdx.x * 4;
  __shared__ float red[4][4][64];

  float acc[4] = {0.f, 0.f, 0.f, 0.f};
  const int kb = wv * 256;
  const float* ap = actT + (size_t)kb * NB + lane;

  for (int k = 0; k < 256; k += 8) {
    float hv[8];
#pragma unroll
    for (int q = 0; q < 8; ++q) hv[q] = ap[(k + q) * NB];
#pragma unroll
    for (int c = 0; c < 4; ++c)
      acc[c] = dot8_f32(hv, W + (size_t)(c0 + c) * ND + kb + k, acc[c]);
  }
#pragma unroll
  for (int c = 0; c < 4; ++c) red[wv][c][lane] = acc[c];
  __syncthreads();

  const int c = tid >> 6, b = tid & 63;
  float z = red[0][c][b] + red[1][c][b] + red[2][c][b] + red[3][c][b];
  z += bias[c0 + c];
  float g = 2.f * sigf(z);
  float m;
  if (EMB) m = emb[(size_t)tok[b] * ND + (c0 + c)];
  else     m = multT[(size_t)(c0 + c) * NB + b];
  outT[(size_t)(c0 + c) * NB + b] = g * m;
}

__global__ __launch_bounds__(256) void lstm_gates2(
    const float* __restrict__ xT, const float* __restrict__ hT,
    const float* __restrict__ Wih, const float* __restrict__ Whh,
    const float* __restrict__ bih, const float* __restrict__ bhh,
    float* __restrict__ cT, float* __restrict__ hOut)
{
  const int tid = threadIdx.x;
  const int wv = tid >> 6, lane = tid & 63;
  const int j0 = blockIdx.x * 2;
  __shared__ float red[4][16][64];
  float acc[16];
#pragma unroll
  for (int i = 0; i < 16; ++i) acc[i] = 0.f;
  const int kb = wv * 256;
  const float* xp = xT + (size_t)kb * NB + lane;
  const float* hp = hT + (size_t)kb * NB + lane;

  for (int k = 0; k < 256; k += 8) {
    float xv[8], hv[8];
#pragma unroll
    for (int q = 0; q < 8; ++q) { xv[q] = xp[(k + q) * NB]; hv[q] = hp[(k + q) * NB]; }
#pragma unroll
    for (int jj = 0; jj < 2; ++jj)
#pragma unroll
      for (int g = 0; g < 4; ++g) {
        const size_t row = (size_t)(g * ND + j0 + jj) * ND + kb + k;
        acc[jj * 8 + g]     = dot8_f32(xv, Wih + row, acc[jj * 8 + g]);
        acc[jj * 8 + 4 + g] = dot8_f32(hv, Whh + row, acc[jj * 8 + 4 + g]);
      }
  }
#pragma unroll
  for (int i = 0; i < 16; ++i) red[wv][i][lane] = acc[i];
  __syncthreads();

  if (tid < 128) {
    const int b = tid & 63, jj = tid >> 6;
    const int j = j0 + jj;
    float pre[4];
#pragma unroll
    for (int g = 0; g < 4; ++g) {
      float s = 0.f;
#pragma unroll
      for (int w = 0; w < 4; ++w) s += red[w][jj * 8 + g][b] + red[w][jj * 8 + 4 + g][b];
      pre[g] = s + bih[g * ND + j] + bhh[g * ND + j];
    }
    float iv = sigf(pre[0]), fv = sigf(pre[1]);
    float gv = tanhf(pre[2]), ov = sigf(pre[3]);
    float cn = fv * cT[(size_t)j * NB + b] + iv * gv;
    float hn = ov * tanhf(cn);
    cT[(size_t)j * NB + b] = cn;
    hOut[(size_t)j * NB + b] = hn;
  }
}

__global__ __launch_bounds__(256) void decode_k(
    const float* __restrict__ hT, const float* __restrict__ W,
    const float* __restrict__ decb, float* __restrict__ out)
{
  const int tid = threadIdx.x;
  const int wv = tid >> 6, lane = tid & 63;
  const int v0 = blockIdx.x * 4;
  __shared__ float red[4][4][64];
  float acc[4] = {0.f, 0.f, 0.f, 0.f};
  const int kb = wv * 256;
  const float* hp = hT + (size_t)kb * NB + lane;

  for (int k = 0; k < 256; k += 8) {
    float hv[8];
#pragma unroll
    for (int q = 0; q < 8; ++q) hv[q] = hp[(k + q) * NB];
#pragma unroll
    for (int c = 0; c < 4; ++c)
      acc[c] = dot8_f32(hv, W + (size_t)(v0 + c) * ND + kb + k, acc[c]);
  }
#pragma unroll
  for (int c = 0; c < 4; ++c) red[wv][c][lane] = acc[c];
  __syncthreads();

  const int c = tid >> 6, b = tid & 63;
  float z = red[0][c][b] + red[1][c][b] + red[2][c][b] + red[3][c][b];
  z += decb[v0 + c];
  out[(size_t)b * NV + v0 + c] = z;
}

// ---- batched decode GEMM over the whole h-history ----
__global__ __launch_bounds__(256) void decode_gemm(
    const float* __restrict__ A,      // [t][k][b]
    const float* __restrict__ Bw,     // [n][k]
    const float* __restrict__ bias,
    float* __restrict__ C)            // [t][b][n]
{
  const int tid = threadIdx.x;
  const int bid = blockIdx.x;
  const int mt = bid & 255;
  const int nt = bid >> 8;
  const int n0 = nt * 64;

  __shared__ float As[2048];
  __shared__ float Bs[2048];

  const int tm = tid >> 4, tn = tid & 15;
  float acc[4][4] = {{0.f}};
  const float* Abase = A + (size_t)mt * (ND * NB);

  for (int k0 = 0; k0 < ND; k0 += 32) {
    __syncthreads();
    {
      const float4* src = (const float4*)(Abase + (size_t)k0 * NB);
      ((float4*)As)[tid] = src[tid];
      ((float4*)As)[tid + 256] = src[tid + 256];
    }
#pragma unroll
    for (int i = 0; i < 2; ++i) {
      int f = tid + i * 256;
      int n = f >> 3;
      int kc = f & 7;
      int gn = n0 + n;
      float4 v = make_float4(0.f, 0.f, 0.f, 0.f);
      if (gn < NV) v = *(const float4*)(Bw + (size_t)gn * ND + k0 + kc * 4);
      int k = kc * 4;
      int n4 = n >> 2, nr = n & 3;
      Bs[(k + 0) * 64 + ((n4 ^ ((k + 0) & 7)) << 2) + nr] = v.x;
      Bs[(k + 1) * 64 + ((n4 ^ ((k + 1) & 7)) << 2) + nr] = v.y;
      Bs[(k + 2) * 64 + ((n4 ^ ((k + 2) & 7)) << 2) + nr] = v.z;
      Bs[(k + 3) * 64 + ((n4 ^ ((k + 3) & 7)) << 2) + nr] = v.w;
    }
    __syncthreads();
#pragma unroll
    for (int kk = 0; kk < 32; ++kk) {
      float a4[4], b4[4];
      *(float4*)a4 = *(const float4*)(As + kk * 64 + tm * 4);
      *(float4*)b4 = *(const float4*)(Bs + kk * 64 + ((tn ^ (kk & 7)) << 2));
#pragma unroll
      for (int i = 0; i < 4; ++i)
#pragma unroll
        for (int j = 0; j < 4; ++j)
          acc[i][j] = fmaf(a4[i], b4[j], acc[i][j]);
    }
  }

  const int nb = n0 + tn * 4;
  float db[4];
#pragma unroll
  for (int j = 0; j < 4; ++j) db[j] = (nb + j < NV) ? bias[nb + j] : 0.f;
  float* Crow = C + (size_t)mt * ((size_t)NB * NV);
#pragma unroll
  for (int i = 0; i < 4; ++i) {
    const int b = tm * 4 + i;
    float* cp = Crow + (size_t)b * NV + nb;
    if (nb + 3 < NV) {
      float4 v;
      v.x = acc[i][0] + db[0]; v.y = acc[i][1] + db[1];
      v.z = acc[i][2] + db[2]; v.w = acc[i][3] + db[3];
      *(float4*)cp = v;
    } else {
#pragma unroll
      for (int j = 0; j < 4; ++j)
        if (nb + j < NV) cp[j] = acc[i][j] + db[j];
    }
  }
}

__global__ void finalize(const float* __restrict__ hT, const float* __restrict__ cT,
                         float* __restrict__ out) {
  int i = blockIdx.x * 256 + threadIdx.x;
  int k = i >> 6, b = i & 63;
  size_t base = (size_t)SEQ_LEN * NB * NV;
  out[base + (size_t)b * ND + k] = hT[i];
  out[base + (size_t)NB * ND + (size_t)b * ND + k] = cT[i];
}

extern "C" void kernel_launch(void* const* d_in, const int* in_sizes, int n_in,
                              void* d_out, int out_size, void* d_ws, size_t ws_size,
                              hipStream_t stream)
{
  float* out = (float*)d_out;
  const unsigned long long expect_out = (unsigned long long)SEQ_LEN * NB * NV + 2ull * NB * ND;

  auto flood = [&](float v) {
    unsigned long long n = (unsigned long long)out_size;
    unsigned int g = (unsigned int)((n + 255) / 256);
    floodk<<<g, 256, 0, stream>>>(out, v, n);
  };
  const int expect_sz[14] = {
    SEQ_LEN * NB, NV * ND, 2 * ND * ND, 2 * ND, 2 * ND * ND, 2 * ND,
    4 * ND * ND, 4 * ND * ND, 4 * ND, 4 * ND, NV * ND, NV, NB * ND, NB * ND };
  if (n_in != 14) { flood(1000.f); return; }
  for (int i = 0; i < 14; ++i)
    if (in_sizes[i] != expect_sz[i]) { flood(1100.f + 100.f * i); return; }
  if ((unsigned long long)out_size != expect_out) { flood(2500.f); return; }

  float* ws = (float*)d_ws;
  const size_t SB = (size_t)ND * NB;   // 65536
  if (ws_size < 7 * SB * sizeof(float)) { flood(2600.f); return; }

  const int*   tokens = (const int*)d_in[0];
  const float* emb  = (const float*)d_in[1];
  const float* qw   = (const float*)d_in[2];
  const float* qb   = (const float*)d_in[3];
  const float* rw   = (const float*)d_in[4];
  const float* rb   = (const float*)d_in[5];
  const float* wih  = (const float*)d_in[6];
  const float* whh  = (const float*)d_in[7];
  const float* bih  = (const float*)d_in[8];
  const float* bhh  = (const float*)d_in[9];
  const float* decw = (const float*)d_in[10];
  const float* decb = (const float*)d_in[11];
  const float* h0   = (const float*)d_in[12];
  const float* c0   = (const float*)d_in[13];

  float* xA = ws + 0 * SB;
  float* xB = ws + 1 * SB;
  float* h1 = ws + 2 * SB;
  float* h3 = ws + 3 * SB;
  float* cS = ws + 4 * SB;
  float* hHist = ws + 5 * SB;          // 257 slots
  u32* flags = (u32*)(ws + (5 + SEQ_LEN + 1) * SB);   // 256 x 16 u32 (64B-padded)

  const size_t DH = (size_t)ND * ND;
  const bool big = ws_size >= ((5 + SEQ_LEN + 1) * SB + NBLK * 16) * sizeof(float);

  if (big) {
    init_state<<<256, 256, 0, stream>>>(h0, c0, hHist, cS, flags);
    seq_kernel<<<NBLK, 512, 0, stream>>>(tokens, emb, qw, qb, rw, rb,
                                         wih, whh, bih, bhh,
                                         xA, xB, h1, h3, cS, hHist, flags);
    decode_gemm<<<157 * 256, 256, 0, stream>>>(hHist + SB, decw, decb, out);
    finalize<<<256, 256, 0, stream>>>(hHist + (size_t)SEQ_LEN * SB, cS, out);
  } else {
    float* hA = hHist;
    float* hB = hHist + SB;
    init_state<<<256, 256, 0, stream>>>(h0, c0, hA, cS, flags);
    float* hc = hA;
    float* hn = hB;
    for (int t = 0; t < SEQ_LEN; ++t) {
      const int* tk = tokens + (size_t)t * NB;
      mog_phase<true ><<<256, 256, 0, stream>>>(hc, qw, qb, nullptr, emb, tk, xA);
      mog_phase<false><<<256, 256, 0, stream>>>(xA, rw, rb, hc, nullptr, nullptr, h1);
      mog_phase<false><<<256, 256, 0, stream>>>(h1, qw + DH, qb + ND, xA, nullptr, nullptr, xB);
      mog_phase<false><<<256, 256, 0, stream>>>(xB, rw + DH, rb + ND, h1, nullptr, nullptr, h3);
      lstm_gates2<<<512, 256, 0, stream>>>(xB, h3, wih, whh, bih, bhh, cS, hn);
      decode_k<<<2500, 256, 0, stream>>>(hn, decw, decb, out + (size_t)t * NB * NV);
      float* tmp = hc; hc = hn; hn = tmp;
    }
    finalize<<<256, 256, 0, stream>>>(hc, cS, out);
  }
}

// Round 10
// 52242.456 us; speedup vs baseline: 1.3015x; 1.3015x over previous
//
#include <hip/hip_runtime.h>
#include <hip/hip_bf16.h>

#define SEQ_LEN 256
#define NB 64
#define NV 10000
#define ND 1024
#define NBLK 256

typedef unsigned int u32;
typedef unsigned short u16;

__device__ __forceinline__ float sigf(float z) { return 1.f / (1.f + expf(-z)); }

__device__ __forceinline__ float bflo(u32 u) {
  union { u32 i; float f; } v; v.i = u << 16; return v.f;
}
__device__ __forceinline__ float bfhi(u32 u) {
  union { u32 i; float f; } v; v.i = u & 0xffff0000u; return v.f;
}
__device__ __forceinline__ u16 f2bf(float f) {   // RNE
  u32 u = __float_as_uint(f);
  u32 r = u + 0x7FFFu + ((u >> 16) & 1u);
  return (u16)(r >> 16);
}

// ---- device-coherent (L2-bypass, sc1) scalar accessors for cross-block data ----
__device__ __forceinline__ float ucld(const float* p) {
  u32 v = __hip_atomic_load((const u32*)p, __ATOMIC_RELAXED, __HIP_MEMORY_SCOPE_AGENT);
  union { u32 i; float f; } c; c.i = v; return c.f;
}
__device__ __forceinline__ void ucst(float* p, float x) {
  union { float f; u32 i; } c; c.f = x;
  __hip_atomic_store((u32*)p, c.i, __ATOMIC_RELAXED, __HIP_MEMORY_SCOPE_AGENT);
}

__device__ __forceinline__ float dot8_f32(const float* hv, const float* wp, float acc) {
  float4 w0 = *(const float4*)wp;
  float4 w1 = *(const float4*)(wp + 4);
  acc += hv[0] * w0.x; acc += hv[1] * w0.y; acc += hv[2] * w0.z; acc += hv[3] * w0.w;
  acc += hv[4] * w1.x; acc += hv[5] * w1.y; acc += hv[6] * w1.z; acc += hv[7] * w1.w;
  return acc;
}

// 8 bf16 weights from LDS (wave-uniform address -> broadcast, conflict-free)
__device__ __forceinline__ float dot8_w(const float* hv, const u16* wp, float acc) {
  uint4 wu = *(const uint4*)wp;
  acc = fmaf(hv[0], bflo(wu.x), acc); acc = fmaf(hv[1], bfhi(wu.x), acc);
  acc = fmaf(hv[2], bflo(wu.y), acc); acc = fmaf(hv[3], bfhi(wu.y), acc);
  acc = fmaf(hv[4], bflo(wu.z), acc); acc = fmaf(hv[5], bfhi(wu.z), acc);
  acc = fmaf(hv[6], bflo(wu.w), acc); acc = fmaf(hv[7], bfhi(wu.w), acc);
  return acc;
}

// ---- diagnostic flood (f32 out) ----
__global__ void floodk(float* out, float val, unsigned long long n) {
  unsigned long long i = (unsigned long long)blockIdx.x * 256 + threadIdx.x;
  if (i < n) out[i] = val;
}

// ---- init: transpose states to feature-major, zero barrier flags ----
__global__ void init_state(const float* __restrict__ h0, const float* __restrict__ c0,
                           float* __restrict__ hT, float* __restrict__ cT, u32* flags) {
  int i = blockIdx.x * 256 + threadIdx.x;   // 0..65535
  int k = i >> 6, b = i & 63;
  hT[i] = h0[b * ND + k];
  cT[i] = c0[b * ND + k];
  if (i < NBLK * 16) flags[i] = 0u;         // 64B-padded per-block flags
}

// ================= persistent fused sequence kernel =================
// 256 blocks x 512 thr. Weights bf16 in LDS. Activations exchanged via
// sc1 (L2-bypass, L3-coherent) accesses -> NO fences, L2 never invalidated.
// Barrier: relaxed flag store (own line) + wave-0 poll; __syncthreads drains
// all waves' vmem before the flag store (compiler emits vmcnt(0) at barrier).

__device__ __forceinline__ void fbar(u32* flags, u32 want) {
  __syncthreads();                       // all waves' stores complete
  const int tid = threadIdx.x;
  if (tid == 0)
    __hip_atomic_store(flags + (size_t)blockIdx.x * 16, want,
                       __ATOMIC_RELAXED, __HIP_MEMORY_SCOPE_AGENT);
  if (tid < 64) {
    for (;;) {
      int ok = 1;
#pragma unroll
      for (int i = 0; i < 4; ++i) {
        u32 f = __hip_atomic_load(flags + (size_t)(tid * 4 + i) * 16,
                                  __ATOMIC_RELAXED, __HIP_MEMORY_SCOPE_AGENT);
        ok &= (f >= want);
      }
      if (__all(ok)) break;
      __builtin_amdgcn_s_sleep(1);
    }
  }
  __syncthreads();                       // releases waves 1..7
}

// mog phase: out[c][b] = 2*sig(sum_k act[k][b]*W[c][k] + bias[c]) * mult
template<bool EMB>
__device__ __forceinline__ void mogP(
    const float* __restrict__ actT, const u16* Wl, const float* bL,
    const float* __restrict__ emb, const int* __restrict__ tok,
    const float* __restrict__ multT, float* __restrict__ outT, float* red)
{
  const int tid = threadIdx.x;
  const int wv = tid >> 6, lane = tid & 63;
  const int c0 = blockIdx.x * 4;
  const int kb = wv * 128;
  float acc[4] = {0.f, 0.f, 0.f, 0.f};
  const float* ap = actT + (size_t)kb * NB + lane;

#pragma unroll
  for (int g = 0; g < 4; ++g) {
    float av[32];
#pragma unroll
    for (int q = 0; q < 32; ++q) av[q] = ucld(ap + (g * 32 + q) * NB);
#pragma unroll
    for (int c = 0; c < 4; ++c) {
      const u16* wp = Wl + c * 1024 + kb + g * 32;
#pragma unroll
      for (int h = 0; h < 4; ++h)
        acc[c] = dot8_w(av + h * 8, wp + h * 8, acc[c]);
    }
  }
#pragma unroll
  for (int c = 0; c < 4; ++c) red[(wv * 16 + c) * 64 + lane] = acc[c];
  __syncthreads();

  if (tid < 256) {
    const int c = tid >> 6, b = tid & 63;
    float z = 0.f;
#pragma unroll
    for (int w = 0; w < 8; ++w) z += red[(w * 16 + c) * 64 + b];
    z += bL[c];
    float g = 2.f * sigf(z);
    float m = EMB ? emb[(size_t)tok[b] * ND + (c0 + c)]
                  : ucld(multT + (size_t)(c0 + c) * NB + b);
    ucst(outT + (size_t)(c0 + c) * NB + b, g * m);
  }
}

// gates phase: block owns 4 hidden cols (16 rows r=jj*4+g); waves 0-3 x-half,
// 4-7 h-half. c-state lives in creg (tid<256). bG = bih+bhh presummed.
__device__ __forceinline__ void gatesP(
    const float* __restrict__ xT, const float* __restrict__ hT,
    const u16* wG, const float* bG,
    float& creg, float* __restrict__ hOut, float* red)
{
  const int tid = threadIdx.x;
  const int wv = tid >> 6, lane = tid & 63;
  const int j0 = blockIdx.x * 4;
  const int half = wv >> 2, kq = wv & 3;
  const int kb = kq * 256;
  const float* ap = (half ? hT : xT) + (size_t)kb * NB + lane;
  const u16* Wb = wG + half * (16 * 1024);

  float acc[16];
#pragma unroll
  for (int i = 0; i < 16; ++i) acc[i] = 0.f;

#pragma unroll 2
  for (int g = 0; g < 8; ++g) {
    float av[32];
#pragma unroll
    for (int q = 0; q < 32; ++q) av[q] = ucld(ap + (g * 32 + q) * NB);
#pragma unroll
    for (int r = 0; r < 16; ++r) {
      const u16* wp = Wb + r * 1024 + kb + g * 32;
#pragma unroll
      for (int h = 0; h < 4; ++h)
        acc[r] = dot8_w(av + h * 8, wp + h * 8, acc[r]);
    }
  }
#pragma unroll
  for (int i = 0; i < 16; ++i) red[(wv * 16 + i) * 64 + lane] = acc[i];
  __syncthreads();

  if (tid < 256) {
    const int jj = tid >> 6, b = tid & 63;
    float pre[4];
#pragma unroll
    for (int g = 0; g < 4; ++g) {
      float s = 0.f;
#pragma unroll
      for (int w = 0; w < 8; ++w) s += red[(w * 16 + jj * 4 + g) * 64 + b];
      pre[g] = s + bG[jj * 4 + g];
    }
    float iv = sigf(pre[0]), fv = sigf(pre[1]);
    float gv = tanhf(pre[2]), ov = sigf(pre[3]);
    float cn = fv * creg + iv * gv;
    creg = cn;
    ucst(hOut + (size_t)(j0 + jj) * NB + b, sigf(pre[3]) * tanhf(cn) * 0.f + ov * tanhf(cn));
  }
}

__global__ __launch_bounds__(512) void seq_kernel(
    const int* __restrict__ tokens, const float* __restrict__ emb,
    const float* __restrict__ qw, const float* __restrict__ qb,
    const float* __restrict__ rw, const float* __restrict__ rb,
    const float* __restrict__ wih, const float* __restrict__ whh,
    const float* __restrict__ bih, const float* __restrict__ bhh,
    float* __restrict__ xA, float* __restrict__ xB,
    float* __restrict__ h1, float* __restrict__ h3,
    float* __restrict__ cS, float* __restrict__ hHist, u32* flags)
{
  __shared__ u16 wMog[4 * 4 * 1024];     // 32 KB: [mat][col][k]
  __shared__ u16 wG[2 * 16 * 1024];      // 64 KB: [mat][row r=jj*4+g][k]
  __shared__ float red[8 * 16 * 64];     // 32 KB
  __shared__ float bMog[4][4];           // per-phase col biases
  __shared__ float bGs[16];              // bih+bhh for (jj,g)

  const int tid = threadIdx.x;
  const int c0 = blockIdx.x * 4;
  const size_t DH = (size_t)ND * ND;
  const size_t SB = (size_t)ND * NB;

  // ---- one-time LDS weight fill (f32 -> bf16 RNE) + bias preload ----
  {
    const float* msrc[4] = {qw, rw, qw + DH, rw + DH};
#pragma unroll
    for (int m = 0; m < 4; ++m)
      for (int c = 0; c < 4; ++c) {
        const float* src = msrc[m] + (size_t)(c0 + c) * ND;
        u16* dst = wMog + (m * 4 + c) * 1024;
        for (int k = tid; k < ND; k += 512) dst[k] = f2bf(src[k]);
      }
#pragma unroll
    for (int m = 0; m < 2; ++m) {
      const float* W = m ? whh : wih;
      for (int r = 0; r < 16; ++r) {
        const float* src = W + ((size_t)(r & 3) * ND + c0 + (r >> 2)) * ND;
        u16* dst = wG + (m * 16 + r) * 1024;
        for (int k = tid; k < ND; k += 512) dst[k] = f2bf(src[k]);
      }
    }
    if (tid < 16) {
      int p = tid >> 2, c = tid & 3;
      const float* bs = (p == 0) ? qb : (p == 1) ? rb : (p == 2) ? qb + ND : rb + ND;
      bMog[p][c] = bs[c0 + c];
    }
    if (tid >= 16 && tid < 32) {
      int r = tid - 16;
      int jj = r >> 2, g = r & 3;
      bGs[r] = bih[g * ND + c0 + jj] + bhh[g * ND + c0 + jj];
    }
  }
  float creg = 0.f;
  if (tid < 256) creg = cS[(size_t)(c0 + (tid >> 6)) * NB + (tid & 63)];
  __syncthreads();

  u32 want = 0;
  for (int t = 0; t < SEQ_LEN; ++t) {
    const int* tok = tokens + (size_t)t * NB;
    float* hc = hHist + (size_t)t * SB;
    float* hn = hc + SB;
    mogP<true >(hc, wMog + 0 * 4096, bMog[0], emb, tok, nullptr, xA, red); fbar(flags, ++want);
    mogP<false>(xA, wMog + 1 * 4096, bMog[1], nullptr, nullptr, hc, h1, red); fbar(flags, ++want);
    mogP<false>(h1, wMog + 2 * 4096, bMog[2], nullptr, nullptr, xA, xB, red); fbar(flags, ++want);
    mogP<false>(xB, wMog + 3 * 4096, bMog[3], nullptr, nullptr, h1, h3, red); fbar(flags, ++want);
    gatesP(xB, h3, wG, bGs, creg, hn, red);                                 fbar(flags, ++want);
  }
  if (tid < 256) cS[(size_t)(c0 + (tid >> 6)) * NB + (tid & 63)] = creg;
}

// ================= fallback multi-launch kernels (proven) =================

template<bool EMB>
__global__ __launch_bounds__(256) void mog_phase(
    const float* __restrict__ actT, const float* __restrict__ W,
    const float* __restrict__ bias, const float* __restrict__ multT,
    const float* __restrict__ emb, const int* __restrict__ tok,
    float* __restrict__ outT)
{
  const int tid = threadIdx.x;
  const int wv = tid >> 6;
  const int lane = tid & 63;
  const int c0 = blockIdx.x * 4;
  __shared__ float red[4][4][64];

  float acc[4] = {0.f, 0.f, 0.f, 0.f};
  const int kb = wv * 256;
  const float* ap = actT + (size_t)kb * NB + lane;

  for (int k = 0; k < 256; k += 8) {
    float hv[8];
#pragma unroll
    for (int q = 0; q < 8; ++q) hv[q] = ap[(k + q) * NB];
#pragma unroll
    for (int c = 0; c < 4; ++c)
      acc[c] = dot8_f32(hv, W + (size_t)(c0 + c) * ND + kb + k, acc[c]);
  }
#pragma unroll
  for (int c = 0; c < 4; ++c) red[wv][c][lane] = acc[c];
  __syncthreads();

  const int c = tid >> 6, b = tid & 63;
  float z = red[0][c][b] + red[1][c][b] + red[2][c][b] + red[3][c][b];
  z += bias[c0 + c];
  float g = 2.f * sigf(z);
  float m;
  if (EMB) m = emb[(size_t)tok[b] * ND + (c0 + c)];
  else     m = multT[(size_t)(c0 + c) * NB + b];
  outT[(size_t)(c0 + c) * NB + b] = g * m;
}

__global__ __launch_bounds__(256) void lstm_gates2(
    const float* __restrict__ xT, const float* __restrict__ hT,
    const float* __restrict__ Wih, const float* __restrict__ Whh,
    const float* __restrict__ bih, const float* __restrict__ bhh,
    float* __restrict__ cT, float* __restrict__ hOut)
{
  const int tid = threadIdx.x;
  const int wv = tid >> 6, lane = tid & 63;
  const int j0 = blockIdx.x * 2;
  __shared__ float red[4][16][64];
  float acc[16];
#pragma unroll
  for (int i = 0; i < 16; ++i) acc[i] = 0.f;
  const int kb = wv * 256;
  const float* xp = xT + (size_t)kb * NB + lane;
  const float* hp = hT + (size_t)kb * NB + lane;

  for (int k = 0; k < 256; k += 8) {
    float xv[8], hv[8];
#pragma unroll
    for (int q = 0; q < 8; ++q) { xv[q] = xp[(k + q) * NB]; hv[q] = hp[(k + q) * NB]; }
#pragma unroll
    for (int jj = 0; jj < 2; ++jj)
#pragma unroll
      for (int g = 0; g < 4; ++g) {
        const size_t row = (size_t)(g * ND + j0 + jj) * ND + kb + k;
        acc[jj * 8 + g]     = dot8_f32(xv, Wih + row, acc[jj * 8 + g]);
        acc[jj * 8 + 4 + g] = dot8_f32(hv, Whh + row, acc[jj * 8 + 4 + g]);
      }
  }
#pragma unroll
  for (int i = 0; i < 16; ++i) red[wv][i][lane] = acc[i];
  __syncthreads();

  if (tid < 128) {
    const int b = tid & 63, jj = tid >> 6;
    const int j = j0 + jj;
    float pre[4];
#pragma unroll
    for (int g = 0; g < 4; ++g) {
      float s = 0.f;
#pragma unroll
      for (int w = 0; w < 4; ++w) s += red[w][jj * 8 + g][b] + red[w][jj * 8 + 4 + g][b];
      pre[g] = s + bih[g * ND + j] + bhh[g * ND + j];
    }
    float iv = sigf(pre[0]), fv = sigf(pre[1]);
    float gv = tanhf(pre[2]), ov = sigf(pre[3]);
    float cn = fv * cT[(size_t)j * NB + b] + iv * gv;
    float hn = ov * tanhf(cn);
    cT[(size_t)j * NB + b] = cn;
    hOut[(size_t)j * NB + b] = hn;
  }
}

__global__ __launch_bounds__(256) void decode_k(
    const float* __restrict__ hT, const float* __restrict__ W,
    const float* __restrict__ decb, float* __restrict__ out)
{
  const int tid = threadIdx.x;
  const int wv = tid >> 6, lane = tid & 63;
  const int v0 = blockIdx.x * 4;
  __shared__ float red[4][4][64];
  float acc[4] = {0.f, 0.f, 0.f, 0.f};
  const int kb = wv * 256;
  const float* hp = hT + (size_t)kb * NB + lane;

  for (int k = 0; k < 256; k += 8) {
    float hv[8];
#pragma unroll
    for (int q = 0; q < 8; ++q) hv[q] = hp[(k + q) * NB];
#pragma unroll
    for (int c = 0; c < 4; ++c)
      acc[c] = dot8_f32(hv, W + (size_t)(v0 + c) * ND + kb + k, acc[c]);
  }
#pragma unroll
  for (int c = 0; c < 4; ++c) red[wv][c][lane] = acc[c];
  __syncthreads();

  const int c = tid >> 6, b = tid & 63;
  float z = red[0][c][b] + red[1][c][b] + red[2][c][b] + red[3][c][b];
  z += decb[v0 + c];
  out[(size_t)b * NV + v0 + c] = z;
}

// ---- batched decode GEMM over the whole h-history ----
__global__ __launch_bounds__(256) void decode_gemm(
    const float* __restrict__ A,      // [t][k][b]
    const float* __restrict__ Bw,     // [n][k]
    const float* __restrict__ bias,
    float* __restrict__ C)            // [t][b][n]
{
  const int tid = threadIdx.x;
  const int bid = blockIdx.x;
  const int mt = bid & 255;
  const int nt = bid >> 8;
  const int n0 = nt * 64;

  __shared__ float As[2048];
  __shared__ float Bs[2048];

  const int tm = tid >> 4, tn = tid & 15;
  float acc[4][4] = {{0.f}};
  const float* Abase = A + (size_t)mt * (ND * NB);

  for (int k0 = 0; k0 < ND; k0 += 32) {
    __syncthreads();
    {
      const float4* src = (const float4*)(Abase + (size_t)k0 * NB);
      ((float4*)As)[tid] = src[tid];
      ((float4*)As)[tid + 256] = src[tid + 256];
    }
#pragma unroll
    for (int i = 0; i < 2; ++i) {
      int f = tid + i * 256;
      int n = f >> 3;
      int kc = f & 7;
      int gn = n0 + n;
      float4 v = make_float4(0.f, 0.f, 0.f, 0.f);
      if (gn < NV) v = *(const float4*)(Bw + (size_t)gn * ND + k0 + kc * 4);
      int k = kc * 4;
      int n4 = n >> 2, nr = n & 3;
      Bs[(k + 0) * 64 + ((n4 ^ ((k + 0) & 7)) << 2) + nr] = v.x;
      Bs[(k + 1) * 64 + ((n4 ^ ((k + 1) & 7)) << 2) + nr] = v.y;
      Bs[(k + 2) * 64 + ((n4 ^ ((k + 2) & 7)) << 2) + nr] = v.z;
      Bs[(k + 3) * 64 + ((n4 ^ ((k + 3) & 7)) << 2) + nr] = v.w;
    }
    __syncthreads();
#pragma unroll
    for (int kk = 0; kk < 32; ++kk) {
      float a4[4], b4[4];
      *(float4*)a4 = *(const float4*)(As + kk * 64 + tm * 4);
      *(float4*)b4 = *(const float4*)(Bs + kk * 64 + ((tn ^ (kk & 7)) << 2));
#pragma unroll
      for (int i = 0; i < 4; ++i)
#pragma unroll
        for (int j = 0; j < 4; ++j)
          acc[i][j] = fmaf(a4[i], b4[j], acc[i][j]);
    }
  }

  const int nb = n0 + tn * 4;
  float db[4];
#pragma unroll
  for (int j = 0; j < 4; ++j) db[j] = (nb + j < NV) ? bias[nb + j] : 0.f;
  float* Crow = C + (size_t)mt * ((size_t)NB * NV);
#pragma unroll
  for (int i = 0; i < 4; ++i) {
    const int b = tm * 4 + i;
    float* cp = Crow + (size_t)b * NV + nb;
    if (nb + 3 < NV) {
      float4 v;
      v.x = acc[i][0] + db[0]; v.y = acc[i][1] + db[1];
      v.z = acc[i][2] + db[2]; v.w = acc[i][3] + db[3];
      *(float4*)cp = v;
    } else {
#pragma unroll
      for (int j = 0; j < 4; ++j)
        if (nb + j < NV) cp[j] = acc[i][j] + db[j];
    }
  }
}

__global__ void finalize(const float* __restrict__ hT, const float* __restrict__ cT,
                         float* __restrict__ out) {
  int i = blockIdx.x * 256 + threadIdx.x;
  int k = i >> 6, b = i & 63;
  size_t base = (size_t)SEQ_LEN * NB * NV;
  out[base + (size_t)b * ND + k] = hT[i];
  out[base + (size_t)NB * ND + (size_t)b * ND + k] = cT[i];
}

extern "C" void kernel_launch(void* const* d_in, const int* in_sizes, int n_in,
                              void* d_out, int out_size, void* d_ws, size_t ws_size,
                              hipStream_t stream)
{
  float* out = (float*)d_out;
  const unsigned long long expect_out = (unsigned long long)SEQ_LEN * NB * NV + 2ull * NB * ND;

  auto flood = [&](float v) {
    unsigned long long n = (unsigned long long)out_size;
    unsigned int g = (unsigned int)((n + 255) / 256);
    floodk<<<g, 256, 0, stream>>>(out, v, n);
  };
  const int expect_sz[14] = {
    SEQ_LEN * NB, NV * ND, 2 * ND * ND, 2 * ND, 2 * ND * ND, 2 * ND,
    4 * ND * ND, 4 * ND * ND, 4 * ND, 4 * ND, NV * ND, NV, NB * ND, NB * ND };
  if (n_in != 14) { flood(1000.f); return; }
  for (int i = 0; i < 14; ++i)
    if (in_sizes[i] != expect_sz[i]) { flood(1100.f + 100.f * i); return; }
  if ((unsigned long long)out_size != expect_out) { flood(2500.f); return; }

  float* ws = (float*)d_ws;
  const size_t SB = (size_t)ND * NB;   // 65536
  if (ws_size < 7 * SB * sizeof(float)) { flood(2600.f); return; }

  const int*   tokens = (const int*)d_in[0];
  const float* emb  = (const float*)d_in[1];
  const float* qw   = (const float*)d_in[2];
  const float* qb   = (const float*)d_in[3];
  const float* rw   = (const float*)d_in[4];
  const float* rb   = (const float*)d_in[5];
  const float* wih  = (const float*)d_in[6];
  const float* whh  = (const float*)d_in[7];
  const float* bih  = (const float*)d_in[8];
  const float* bhh  = (const float*)d_in[9];
  const float* decw = (const float*)d_in[10];
  const float* decb = (const float*)d_in[11];
  const float* h0   = (const float*)d_in[12];
  const float* c0   = (const float*)d_in[13];

  float* xA = ws + 0 * SB;
  float* xB = ws + 1 * SB;
  float* h1 = ws + 2 * SB;
  float* h3 = ws + 3 * SB;
  float* cS = ws + 4 * SB;
  float* hHist = ws + 5 * SB;          // 257 slots
  u32* flags = (u32*)(ws + (5 + SEQ_LEN + 1) * SB);   // 256 x 16 u32 (64B-padded)

  const size_t DH = (size_t)ND * ND;
  const bool big = ws_size >= ((5 + SEQ_LEN + 1) * SB + NBLK * 16) * sizeof(float);

  if (big) {
    init_state<<<256, 256, 0, stream>>>(h0, c0, hHist, cS, flags);
    seq_kernel<<<NBLK, 512, 0, stream>>>(tokens, emb, qw, qb, rw, rb,
                                         wih, whh, bih, bhh,
                                         xA, xB, h1, h3, cS, hHist, flags);
    decode_gemm<<<157 * 256, 256, 0, stream>>>(hHist + SB, decw, decb, out);
    finalize<<<256, 256, 0, stream>>>(hHist + (size_t)SEQ_LEN * SB, cS, out);
  } else {
    float* hA = hHist;
    float* hB = hHist + SB;
    init_state<<<256, 256, 0, stream>>>(h0, c0, hA, cS, flags);
    float* hc = hA;
    float* hn = hB;
    for (int t = 0; t < SEQ_LEN; ++t) {
      const int* tk = tokens + (size_t)t * NB;
      mog_phase<true ><<<256, 256, 0, stream>>>(hc, qw, qb, nullptr, emb, tk, xA);
      mog_phase<false><<<256, 256, 0, stream>>>(xA, rw, rb, hc, nullptr, nullptr, h1);
      mog_phase<false><<<256, 256, 0, stream>>>(h1, qw + DH, qb + ND, xA, nullptr, nullptr, xB);
      mog_phase<false><<<256, 256, 0, stream>>>(xB, rw + DH, rb + ND, h1, nullptr, nullptr, h3);
      lstm_gates2<<<512, 256, 0, stream>>>(xB, h3, wih, whh, bih, bhh, cS, hn);
      decode_k<<<2500, 256, 0, stream>>>(hn, decw, decb, out + (size_t)t * NB * NV);
      float* tmp = hc; hc = hn; hn = tmp;
    }
    finalize<<<256, 256, 0, stream>>>(hc, cS, out);
  }
}

// Round 11
// 24640.334 us; speedup vs baseline: 2.7595x; 2.1202x over previous
//
#include <hip/hip_runtime.h>
#include <hip/hip_bf16.h>

#define SEQ_LEN 256
#define NB 64
#define NV 10000
#define ND 1024
#define NBLK 256

typedef unsigned int u32;
typedef unsigned short u16;
typedef u32 u32x4 __attribute__((ext_vector_type(4)));

__device__ __forceinline__ float sigf(float z) { return 1.f / (1.f + expf(-z)); }

__device__ __forceinline__ float bflo(u32 u) {
  union { u32 i; float f; } v; v.i = u << 16; return v.f;
}
__device__ __forceinline__ float bfhi(u32 u) {
  union { u32 i; float f; } v; v.i = u & 0xffff0000u; return v.f;
}
__device__ __forceinline__ u16 f2bf(float f) {   // RNE
  u32 u = __float_as_uint(f);
  u32 r = u + 0x7FFFu + ((u >> 16) & 1u);
  return (u16)(r >> 16);
}

// ---- sc1 (device-coherent, L2-bypass) exchange primitives ----
// Load 64B (16 u32 = 32 bf16) per lane, unpack to f32.
__device__ __forceinline__ void ld_grp(const u32* p, float* av /*32*/) {
  u32x4 a, b, c, d;
  asm volatile(
      "global_load_dwordx4 %0, %4, off sc1\n\t"
      "global_load_dwordx4 %1, %4, off offset:16 sc1\n\t"
      "global_load_dwordx4 %2, %4, off offset:32 sc1\n\t"
      "global_load_dwordx4 %3, %4, off offset:48 sc1\n\t"
      "s_waitcnt vmcnt(0)"
      : "=&v"(a), "=&v"(b), "=&v"(c), "=&v"(d)
      : "v"(p)
      : "memory");
  u32 q[16];
  *(u32x4*)(q) = a; *(u32x4*)(q + 4) = b; *(u32x4*)(q + 8) = c; *(u32x4*)(q + 12) = d;
#pragma unroll
  for (int i = 0; i < 16; ++i) { av[2 * i] = bflo(q[i]); av[2 * i + 1] = bfhi(q[i]); }
}
__device__ __forceinline__ u32 ld_uc1(const u32* p) {
  u32 r;
  asm volatile("global_load_dword %0, %1, off sc1\n\ts_waitcnt vmcnt(0)"
               : "=&v"(r) : "v"(p) : "memory");
  return r;
}
__device__ __forceinline__ void st_uc1(u32* p, u32 v) {
  asm volatile("global_store_dword %0, %1, off sc1" :: "v"(p), "v"(v) : "memory");
}

__device__ __forceinline__ float dot8_f32(const float* hv, const float* wp, float acc) {
  float4 w0 = *(const float4*)wp;
  float4 w1 = *(const float4*)(wp + 4);
  acc += hv[0] * w0.x; acc += hv[1] * w0.y; acc += hv[2] * w0.z; acc += hv[3] * w0.w;
  acc += hv[4] * w1.x; acc += hv[5] * w1.y; acc += hv[6] * w1.z; acc += hv[7] * w1.w;
  return acc;
}
// 8 bf16 weights from LDS (wave-uniform broadcast), f32 acts in regs
__device__ __forceinline__ float dot8_w(const float* hv, const u16* wp, float acc) {
  uint4 wu = *(const uint4*)wp;
  acc = fmaf(hv[0], bflo(wu.x), acc); acc = fmaf(hv[1], bfhi(wu.x), acc);
  acc = fmaf(hv[2], bflo(wu.y), acc); acc = fmaf(hv[3], bfhi(wu.y), acc);
  acc = fmaf(hv[4], bflo(wu.z), acc); acc = fmaf(hv[5], bfhi(wu.z), acc);
  acc = fmaf(hv[6], bflo(wu.w), acc); acc = fmaf(hv[7], bfhi(wu.w), acc);
  return acc;
}

// ---- diagnostic flood (f32 out) ----
__global__ void floodk(float* out, float val, unsigned long long n) {
  unsigned long long i = (unsigned long long)blockIdx.x * 256 + threadIdx.x;
  if (i < n) out[i] = val;
}

// ---- init: states to feature-major f32 + batch-major bf16; zero flags ----
__global__ void init_state(const float* __restrict__ h0, const float* __restrict__ c0,
                           float* __restrict__ hT, float* __restrict__ cT,
                           u16* __restrict__ hx16, u32* flags) {
  int i = blockIdx.x * 256 + threadIdx.x;   // 0..65535
  int k = i >> 6, b = i & 63;
  float hv = h0[b * ND + k];
  hT[i] = hv;
  cT[i] = c0[b * ND + k];
  hx16[b * ND + k] = f2bf(hv);
  if (i < NBLK * 16) flags[i] = 0u;
}

// ================= persistent fused sequence kernel =================
// 256 blocks x 512 thr. Weights bf16 in LDS. Activations exchanged as
// packed bf16 [b][k/2] u32 via sc1 dwordx4 bursts. No fences anywhere.

__device__ __forceinline__ void fbar(u32* flags, u32 want) {
  asm volatile("s_waitcnt vmcnt(0)" ::: "memory");
  __syncthreads();
  const int tid = threadIdx.x;
  if (tid == 0)
    __hip_atomic_store(flags + (size_t)blockIdx.x * 16, want,
                       __ATOMIC_RELAXED, __HIP_MEMORY_SCOPE_AGENT);
  if (tid < 64) {
    for (;;) {
      int ok = 1;
#pragma unroll
      for (int i = 0; i < 4; ++i) {
        u32 f = __hip_atomic_load(flags + (size_t)(tid * 4 + i) * 16,
                                  __ATOMIC_RELAXED, __HIP_MEMORY_SCOPE_AGENT);
        ok &= (f >= want);
      }
      if (__all(ok)) break;
      __builtin_amdgcn_s_sleep(1);
    }
  }
  __syncthreads();
}

// mog phase: out[c] = 2*sig(act . W[c] + b[c]) * mult[c], c in [c0, c0+4)
// actU/multU/outU: packed bf16 [b][k/2]. Wl: LDS [col][k] bf16.
template<bool EMB>
__device__ __forceinline__ void mogP(
    const u32* __restrict__ actU, const u16* Wl, const float* bL,
    const float* __restrict__ emb, const int* __restrict__ tok,
    const u32* __restrict__ multU, u32* __restrict__ outU,
    float* red, float* vals)
{
  const int tid = threadIdx.x;
  const int wv = tid >> 6, lane = tid & 63;
  const int c0 = blockIdx.x * 4;
  const int kb = wv * 128;                       // this wave's k-chunk
  const u32* ap = actU + (size_t)lane * 512 + (kb >> 1);
  float acc[4] = {0.f, 0.f, 0.f, 0.f};

#pragma unroll
  for (int g = 0; g < 4; ++g) {                  // 4 groups x 32 k
    float av[32];
    ld_grp(ap + g * 16, av);
#pragma unroll
    for (int c = 0; c < 4; ++c) {
      const u16* wp = Wl + c * 1024 + kb + g * 32;
#pragma unroll
      for (int h = 0; h < 4; ++h)
        acc[c] = dot8_w(av + h * 8, wp + h * 8, acc[c]);
    }
  }
#pragma unroll
  for (int c = 0; c < 4; ++c) red[(wv * 16 + c) * 64 + lane] = acc[c];
  __syncthreads();

  if (tid < 256) {
    const int c = tid >> 6, b = tid & 63;
    float z = 0.f;
#pragma unroll
    for (int w = 0; w < 8; ++w) z += red[(w * 16 + c) * 64 + b];
    z += bL[c];
    float g2 = 2.f * sigf(z);
    float m;
    if (EMB) {
      m = emb[(size_t)tok[b] * ND + (c0 + c)];
    } else {
      u32 mu = ld_uc1(multU + (size_t)b * 512 + ((c0 + c) >> 1));
      m = (c & 1) ? bfhi(mu) : bflo(mu);
    }
    vals[c * 64 + b] = g2 * m;
  }
  __syncthreads();

  if (tid < 128) {
    const int cp = tid >> 6, b = tid & 63;
    float lo = vals[(2 * cp) * 64 + b];
    float hi = vals[(2 * cp + 1) * 64 + b];
    u32 pk = (u32)f2bf(lo) | ((u32)f2bf(hi) << 16);
    st_uc1(outU + (size_t)b * 512 + (c0 >> 1) + cp, pk);
  }
}

// gates: block owns 4 hidden cols (16 rows r=jj*4+g). waves 0-3 x, 4-7 h.
__device__ __forceinline__ void gatesP(
    const u32* __restrict__ xU, const u32* __restrict__ hU,
    const u16* wG, const float* bG, float& creg,
    float* __restrict__ hHistN, u32* __restrict__ hxU,
    float* red, float* vals)
{
  const int tid = threadIdx.x;
  const int wv = tid >> 6, lane = tid & 63;
  const int j0 = blockIdx.x * 4;
  const int half = wv >> 2, kq = wv & 3;
  const int kb = kq * 256;
  const u32* ap = (half ? hU : xU) + (size_t)lane * 512 + (kb >> 1);
  const u16* Wb = wG + half * (16 * 1024);

  float acc[16];
#pragma unroll
  for (int i = 0; i < 16; ++i) acc[i] = 0.f;

#pragma unroll
  for (int g = 0; g < 8; ++g) {                  // 8 groups x 32 k
    float av[32];
    ld_grp(ap + g * 16, av);
#pragma unroll
    for (int r = 0; r < 16; ++r) {
      const u16* wp = Wb + r * 1024 + kb + g * 32;
#pragma unroll
      for (int h = 0; h < 4; ++h)
        acc[r] = dot8_w(av + h * 8, wp + h * 8, acc[r]);
    }
  }
#pragma unroll
  for (int i = 0; i < 16; ++i) red[(wv * 16 + i) * 64 + lane] = acc[i];
  __syncthreads();

  if (tid < 256) {
    const int jj = tid >> 6, b = tid & 63;
    float pre[4];
#pragma unroll
    for (int g = 0; g < 4; ++g) {
      float s = 0.f;
#pragma unroll
      for (int w = 0; w < 8; ++w) s += red[(w * 16 + jj * 4 + g) * 64 + b];
      pre[g] = s + bG[jj * 4 + g];
    }
    float iv = sigf(pre[0]), fv = sigf(pre[1]);
    float gv = tanhf(pre[2]), ov = sigf(pre[3]);
    float cn = fv * creg + iv * gv;
    creg = cn;
    float hn = ov * tanhf(cn);
    hHistN[(size_t)(j0 + jj) * NB + b] = hn;     // f32, decode-only (normal store)
    vals[jj * 64 + b] = hn;
  }
  __syncthreads();

  if (tid < 128) {
    const int cp = tid >> 6, b = tid & 63;
    float lo = vals[(2 * cp) * 64 + b];
    float hi = vals[(2 * cp + 1) * 64 + b];
    u32 pk = (u32)f2bf(lo) | ((u32)f2bf(hi) << 16);
    st_uc1(hxU + (size_t)b * 512 + (j0 >> 1) + cp, pk);
  }
}

__global__ __launch_bounds__(512) void seq_kernel(
    const int* __restrict__ tokens, const float* __restrict__ emb,
    const float* __restrict__ qw, const float* __restrict__ qb,
    const float* __restrict__ rw, const float* __restrict__ rb,
    const float* __restrict__ wih, const float* __restrict__ whh,
    const float* __restrict__ bih, const float* __restrict__ bhh,
    u32* __restrict__ hxU, u32* __restrict__ xAU, u32* __restrict__ h1U,
    u32* __restrict__ xBU, u32* __restrict__ h3U,
    float* __restrict__ cS, float* __restrict__ hHist, u32* flags)
{
  __shared__ u16 wMog[4 * 4 * 1024];     // 32 KB: [mat][col][k]
  __shared__ u16 wG[2 * 16 * 1024];      // 64 KB: [mat][row r=jj*4+g][k]
  __shared__ float red[8 * 16 * 64];     // 32 KB
  __shared__ float vals[256];
  __shared__ float bMog[4][4];
  __shared__ float bGs[16];

  const int tid = threadIdx.x;
  const int c0 = blockIdx.x * 4;
  const size_t DH = (size_t)ND * ND;
  const size_t SB = (size_t)ND * NB;

  // ---- one-time LDS weight fill (f32 -> bf16 RNE) + bias preload ----
  {
    const float* msrc[4] = {qw, rw, qw + DH, rw + DH};
#pragma unroll
    for (int m = 0; m < 4; ++m)
      for (int c = 0; c < 4; ++c) {
        const float* src = msrc[m] + (size_t)(c0 + c) * ND;
        u16* dst = wMog + (m * 4 + c) * 1024;
        for (int k = tid; k < ND; k += 512) dst[k] = f2bf(src[k]);
      }
#pragma unroll
    for (int m = 0; m < 2; ++m) {
      const float* W = m ? whh : wih;
      for (int r = 0; r < 16; ++r) {
        const float* src = W + ((size_t)(r & 3) * ND + c0 + (r >> 2)) * ND;
        u16* dst = wG + (m * 16 + r) * 1024;
        for (int k = tid; k < ND; k += 512) dst[k] = f2bf(src[k]);
      }
    }
    if (tid < 16) {
      int p = tid >> 2, c = tid & 3;
      const float* bs = (p == 0) ? qb : (p == 1) ? rb : (p == 2) ? qb + ND : rb + ND;
      bMog[p][c] = bs[c0 + c];
    }
    if (tid >= 16 && tid < 32) {
      int r = tid - 16;
      int jj = r >> 2, g = r & 3;
      bGs[r] = bih[g * ND + c0 + jj] + bhh[g * ND + c0 + jj];
    }
  }
  float creg = 0.f;
  if (tid < 256) creg = cS[(size_t)(c0 + (tid >> 6)) * NB + (tid & 63)];
  __syncthreads();

  u32 want = 0;
  for (int t = 0; t < SEQ_LEN; ++t) {
    const int* tok = tokens + (size_t)t * NB;
    float* hn = hHist + (size_t)(t + 1) * SB;
    mogP<true >(hxU, wMog + 0 * 4096, bMog[0], emb, tok, nullptr, xAU, red, vals); fbar(flags, ++want);
    mogP<false>(xAU, wMog + 1 * 4096, bMog[1], nullptr, nullptr, hxU, h1U, red, vals); fbar(flags, ++want);
    mogP<false>(h1U, wMog + 2 * 4096, bMog[2], nullptr, nullptr, xAU, xBU, red, vals); fbar(flags, ++want);
    mogP<false>(xBU, wMog + 3 * 4096, bMog[3], nullptr, nullptr, h1U, h3U, red, vals); fbar(flags, ++want);
    gatesP(xBU, h3U, wG, bGs, creg, hn, hxU, red, vals);                              fbar(flags, ++want);
  }
  if (tid < 256) cS[(size_t)(c0 + (tid >> 6)) * NB + (tid & 63)] = creg;
}

// ================= fallback multi-launch kernels (proven) =================

template<bool EMB>
__global__ __launch_bounds__(256) void mog_phase(
    const float* __restrict__ actT, const float* __restrict__ W,
    const float* __restrict__ bias, const float* __restrict__ multT,
    const float* __restrict__ emb, const int* __restrict__ tok,
    float* __restrict__ outT)
{
  const int tid = threadIdx.x;
  const int wv = tid >> 6;
  const int lane = tid & 63;
  const int c0 = blockIdx.x * 4;
  __shared__ float red[4][4][64];

  float acc[4] = {0.f, 0.f, 0.f, 0.f};
  const int kb = wv * 256;
  const float* ap = actT + (size_t)kb * NB + lane;

  for (int k = 0; k < 256; k += 8) {
    float hv[8];
#pragma unroll
    for (int q = 0; q < 8; ++q) hv[q] = ap[(k + q) * NB];
#pragma unroll
    for (int c = 0; c < 4; ++c)
      acc[c] = dot8_f32(hv, W + (size_t)(c0 + c) * ND + kb + k, acc[c]);
  }
#pragma unroll
  for (int c = 0; c < 4; ++c) red[wv][c][lane] = acc[c];
  __syncthreads();

  const int c = tid >> 6, b = tid & 63;
  float z = red[0][c][b] + red[1][c][b] + red[2][c][b] + red[3][c][b];
  z += bias[c0 + c];
  float g = 2.f * sigf(z);
  float m;
  if (EMB) m = emb[(size_t)tok[b] * ND + (c0 + c)];
  else     m = multT[(size_t)(c0 + c) * NB + b];
  outT[(size_t)(c0 + c) * NB + b] = g * m;
}

__global__ __launch_bounds__(256) void lstm_gates2(
    const float* __restrict__ xT, const float* __restrict__ hT,
    const float* __restrict__ Wih, const float* __restrict__ Whh,
    const float* __restrict__ bih, const float* __restrict__ bhh,
    float* __restrict__ cT, float* __restrict__ hOut)
{
  const int tid = threadIdx.x;
  const int wv = tid >> 6, lane = tid & 63;
  const int j0 = blockIdx.x * 2;
  __shared__ float red[4][16][64];
  float acc[16];
#pragma unroll
  for (int i = 0; i < 16; ++i) acc[i] = 0.f;
  const int kb = wv * 256;
  const float* xp = xT + (size_t)kb * NB + lane;
  const float* hp = hT + (size_t)kb * NB + lane;

  for (int k = 0; k < 256; k += 8) {
    float xv[8], hv[8];
#pragma unroll
    for (int q = 0; q < 8; ++q) { xv[q] = xp[(k + q) * NB]; hv[q] = hp[(k + q) * NB]; }
#pragma unroll
    for (int jj = 0; jj < 2; ++jj)
#pragma unroll
      for (int g = 0; g < 4; ++g) {
        const size_t row = (size_t)(g * ND + j0 + jj) * ND + kb + k;
        acc[jj * 8 + g]     = dot8_f32(xv, Wih + row, acc[jj * 8 + g]);
        acc[jj * 8 + 4 + g] = dot8_f32(hv, Whh + row, acc[jj * 8 + 4 + g]);
      }
  }
#pragma unroll
  for (int i = 0; i < 16; ++i) red[wv][i][lane] = acc[i];
  __syncthreads();

  if (tid < 128) {
    const int b = tid & 63, jj = tid >> 6;
    const int j = j0 + jj;
    float pre[4];
#pragma unroll
    for (int g = 0; g < 4; ++g) {
      float s = 0.f;
#pragma unroll
      for (int w = 0; w < 4; ++w) s += red[w][jj * 8 + g][b] + red[w][jj * 8 + 4 + g][b];
      pre[g] = s + bih[g * ND + j] + bhh[g * ND + j];
    }
    float iv = sigf(pre[0]), fv = sigf(pre[1]);
    float gv = tanhf(pre[2]), ov = sigf(pre[3]);
    float cn = fv * cT[(size_t)j * NB + b] + iv * gv;
    float hn = ov * tanhf(cn);
    cT[(size_t)j * NB + b] = cn;
    hOut[(size_t)j * NB + b] = hn;
  }
}

__global__ __launch_bounds__(256) void decode_k(
    const float* __restrict__ hT, const float* __restrict__ W,
    const float* __restrict__ decb, float* __restrict__ out)
{
  const int tid = threadIdx.x;
  const int wv = tid >> 6, lane = tid & 63;
  const int v0 = blockIdx.x * 4;
  __shared__ float red[4][4][64];
  float acc[4] = {0.f, 0.f, 0.f, 0.f};
  const int kb = wv * 256;
  const float* hp = hT + (size_t)kb * NB + lane;

  for (int k = 0; k < 256; k += 8) {
    float hv[8];
#pragma unroll
    for (int q = 0; q < 8; ++q) hv[q] = hp[(k + q) * NB];
#pragma unroll
    for (int c = 0; c < 4; ++c)
      acc[c] = dot8_f32(hv, W + (size_t)(v0 + c) * ND + kb + k, acc[c]);
  }
#pragma unroll
  for (int c = 0; c < 4; ++c) red[wv][c][lane] = acc[c];
  __syncthreads();

  const int c = tid >> 6, b = tid & 63;
  float z = red[0][c][b] + red[1][c][b] + red[2][c][b] + red[3][c][b];
  z += decb[v0 + c];
  out[(size_t)b * NV + v0 + c] = z;
}

// ---- batched decode GEMM over the whole h-history ----
__global__ __launch_bounds__(256) void decode_gemm(
    const float* __restrict__ A,      // [t][k][b]
    const float* __restrict__ Bw,     // [n][k]
    const float* __restrict__ bias,
    float* __restrict__ C)            // [t][b][n]
{
  const int tid = threadIdx.x;
  const int bid = blockIdx.x;
  const int mt = bid & 255;
  const int nt = bid >> 8;
  const int n0 = nt * 64;

  __shared__ float As[2048];
  __shared__ float Bs[2048];

  const int tm = tid >> 4, tn = tid & 15;
  float acc[4][4] = {{0.f}};
  const float* Abase = A + (size_t)mt * (ND * NB);

  for (int k0 = 0; k0 < ND; k0 += 32) {
    __syncthreads();
    {
      const float4* src = (const float4*)(Abase + (size_t)k0 * NB);
      ((float4*)As)[tid] = src[tid];
      ((float4*)As)[tid + 256] = src[tid + 256];
    }
#pragma unroll
    for (int i = 0; i < 2; ++i) {
      int f = tid + i * 256;
      int n = f >> 3;
      int kc = f & 7;
      int gn = n0 + n;
      float4 v = make_float4(0.f, 0.f, 0.f, 0.f);
      if (gn < NV) v = *(const float4*)(Bw + (size_t)gn * ND + k0 + kc * 4);
      int k = kc * 4;
      int n4 = n >> 2, nr = n & 3;
      Bs[(k + 0) * 64 + ((n4 ^ ((k + 0) & 7)) << 2) + nr] = v.x;
      Bs[(k + 1) * 64 + ((n4 ^ ((k + 1) & 7)) << 2) + nr] = v.y;
      Bs[(k + 2) * 64 + ((n4 ^ ((k + 2) & 7)) << 2) + nr] = v.z;
      Bs[(k + 3) * 64 + ((n4 ^ ((k + 3) & 7)) << 2) + nr] = v.w;
    }
    __syncthreads();
#pragma unroll
    for (int kk = 0; kk < 32; ++kk) {
      float a4[4], b4[4];
      *(float4*)a4 = *(const float4*)(As + kk * 64 + tm * 4);
      *(float4*)b4 = *(const float4*)(Bs + kk * 64 + ((tn ^ (kk & 7)) << 2));
#pragma unroll
      for (int i = 0; i < 4; ++i)
#pragma unroll
        for (int j = 0; j < 4; ++j)
          acc[i][j] = fmaf(a4[i], b4[j], acc[i][j]);
    }
  }

  const int nb = n0 + tn * 4;
  float db[4];
#pragma unroll
  for (int j = 0; j < 4; ++j) db[j] = (nb + j < NV) ? bias[nb + j] : 0.f;
  float* Crow = C + (size_t)mt * ((size_t)NB * NV);
#pragma unroll
  for (int i = 0; i < 4; ++i) {
    const int b = tm * 4 + i;
    float* cp = Crow + (size_t)b * NV + nb;
    if (nb + 3 < NV) {
      float4 v;
      v.x = acc[i][0] + db[0]; v.y = acc[i][1] + db[1];
      v.z = acc[i][2] + db[2]; v.w = acc[i][3] + db[3];
      *(float4*)cp = v;
    } else {
#pragma unroll
      for (int j = 0; j < 4; ++j)
        if (nb + j < NV) cp[j] = acc[i][j] + db[j];
    }
  }
}

__global__ void finalize(const float* __restrict__ hT, const float* __restrict__ cT,
                         float* __restrict__ out) {
  int i = blockIdx.x * 256 + threadIdx.x;
  int k = i >> 6, b = i & 63;
  size_t base = (size_t)SEQ_LEN * NB * NV;
  out[base + (size_t)b * ND + k] = hT[i];
  out[base + (size_t)NB * ND + (size_t)b * ND + k] = cT[i];
}

extern "C" void kernel_launch(void* const* d_in, const int* in_sizes, int n_in,
                              void* d_out, int out_size, void* d_ws, size_t ws_size,
                              hipStream_t stream)
{
  float* out = (float*)d_out;
  const unsigned long long expect_out = (unsigned long long)SEQ_LEN * NB * NV + 2ull * NB * ND;

  auto flood = [&](float v) {
    unsigned long long n = (unsigned long long)out_size;
    unsigned int g = (unsigned int)((n + 255) / 256);
    floodk<<<g, 256, 0, stream>>>(out, v, n);
  };
  const int expect_sz[14] = {
    SEQ_LEN * NB, NV * ND, 2 * ND * ND, 2 * ND, 2 * ND * ND, 2 * ND,
    4 * ND * ND, 4 * ND * ND, 4 * ND, 4 * ND, NV * ND, NV, NB * ND, NB * ND };
  if (n_in != 14) { flood(1000.f); return; }
  for (int i = 0; i < 14; ++i)
    if (in_sizes[i] != expect_sz[i]) { flood(1100.f + 100.f * i); return; }
  if ((unsigned long long)out_size != expect_out) { flood(2500.f); return; }

  float* ws = (float*)d_ws;
  const size_t SB = (size_t)ND * NB;   // 65536
  if (ws_size < 7 * SB * sizeof(float)) { flood(2600.f); return; }

  const int*   tokens = (const int*)d_in[0];
  const float* emb  = (const float*)d_in[1];
  const float* qw   = (const float*)d_in[2];
  const float* qb   = (const float*)d_in[3];
  const float* rw   = (const float*)d_in[4];
  const float* rb   = (const float*)d_in[5];
  const float* wih  = (const float*)d_in[6];
  const float* whh  = (const float*)d_in[7];
  const float* bih  = (const float*)d_in[8];
  const float* bhh  = (const float*)d_in[9];
  const float* decw = (const float*)d_in[10];
  const float* decb = (const float*)d_in[11];
  const float* h0   = (const float*)d_in[12];
  const float* c0   = (const float*)d_in[13];

  // big layout: cS | hHist[257] | 5 bf16 exchange buffers | flags
  float* cS    = ws;
  float* hHist = ws + SB;
  u32*   ex    = (u32*)(ws + SB + (size_t)(SEQ_LEN + 1) * SB);
  const size_t EXB = 64 * 512;         // u32 per exchange buffer
  u32* hxU = ex + 0 * EXB;
  u32* xAU = ex + 1 * EXB;
  u32* h1U = ex + 2 * EXB;
  u32* xBU = ex + 3 * EXB;
  u32* h3U = ex + 4 * EXB;
  u32* flags = ex + 5 * EXB;

  const size_t DH = (size_t)ND * ND;
  const size_t need = ((size_t)(1 + SEQ_LEN + 1) * SB) * sizeof(float)
                    + (5 * EXB + NBLK * 16) * sizeof(u32);
  const bool big = ws_size >= need;

  if (big) {
    init_state<<<256, 256, 0, stream>>>(h0, c0, hHist, cS, (u16*)hxU, flags);
    seq_kernel<<<NBLK, 512, 0, stream>>>(tokens, emb, qw, qb, rw, rb,
                                         wih, whh, bih, bhh,
                                         hxU, xAU, h1U, xBU, h3U,
                                         cS, hHist, flags);
    decode_gemm<<<157 * 256, 256, 0, stream>>>(hHist + SB, decw, decb, out);
    finalize<<<256, 256, 0, stream>>>(hHist + (size_t)SEQ_LEN * SB, cS, out);
  } else {
    // fallback: proven multi-launch path
    float* xA = ws + 0 * SB;
    float* xB = ws + 1 * SB;
    float* h1 = ws + 2 * SB;
    float* h3 = ws + 3 * SB;
    float* cSf = ws + 4 * SB;
    float* hA = ws + 5 * SB;
    float* hB = ws + 6 * SB;
    u32* fdummy = (u32*)(ws + 6 * SB);   // unused flags space inside hB is fine pre-init
    init_state<<<256, 256, 0, stream>>>(h0, c0, hA, cSf, (u16*)hB, fdummy);
    float* hc = hA;
    float* hn = hB;
    for (int t = 0; t < SEQ_LEN; ++t) {
      const int* tk = tokens + (size_t)t * NB;
      mog_phase<true ><<<256, 256, 0, stream>>>(hc, qw, qb, nullptr, emb, tk, xA);
      mog_phase<false><<<256, 256, 0, stream>>>(xA, rw, rb, hc, nullptr, nullptr, h1);
      mog_phase<false><<<256, 256, 0, stream>>>(h1, qw + DH, qb + ND, xA, nullptr, nullptr, xB);
      mog_phase<false><<<256, 256, 0, stream>>>(xB, rw + DH, rb + ND, h1, nullptr, nullptr, h3);
      lstm_gates2<<<512, 256, 0, stream>>>(xB, h3, wih, whh, bih, bhh, cSf, hn);
      decode_k<<<2500, 256, 0, stream>>>(hn, decw, decb, out + (size_t)t * NB * NV);
      float* tmp = hc; hc = hn; hn = tmp;
    }
    finalize<<<256, 256, 0, stream>>>(hc, cSf, out);
  }
}

// Round 12
// 15996.870 us; speedup vs baseline: 4.2505x; 1.5403x over previous
//
#include <hip/hip_runtime.h>
#include <hip/hip_bf16.h>

#define SEQ_LEN 256
#define NB 64
#define NV 10000
#define ND 1024
#define NBLK 256

typedef unsigned int u32;
typedef unsigned short u16;
typedef u32 u32x4 __attribute__((ext_vector_type(4)));
typedef short s16x8 __attribute__((ext_vector_type(8)));
typedef float f32x4 __attribute__((ext_vector_type(4)));

__device__ __forceinline__ float sigf(float z) { return 1.f / (1.f + expf(-z)); }

__device__ __forceinline__ float bflo(u32 u) {
  union { u32 i; float f; } v; v.i = u << 16; return v.f;
}
__device__ __forceinline__ float bfhi(u32 u) {
  union { u32 i; float f; } v; v.i = u & 0xffff0000u; return v.f;
}
__device__ __forceinline__ u16 f2bf(float f) {   // RNE
  u32 u = __float_as_uint(f);
  u32 r = u + 0x7FFFu + ((u >> 16) & 1u);
  return (u16)(r >> 16);
}

// ---- sc1 (device-coherent, L2-bypass) primitives ----
__device__ __forceinline__ u32 ld_uc1(const u32* p) {
  u32 r;
  asm volatile("global_load_dword %0, %1, off sc1\n\ts_waitcnt vmcnt(0)"
               : "=&v"(r) : "v"(p) : "memory");
  return r;
}
__device__ __forceinline__ void st_uc1(u32* p, u32 v) {
  asm volatile("global_store_dword %0, %1, off sc1" :: "v"(p), "v"(v) : "memory");
}
// 4 A-fragments (one per M-tile), 16B each, waited.
__device__ __forceinline__ void ld_afrag4(const u32* p0, const u32* p1,
                                          const u32* p2, const u32* p3,
                                          u32x4& a0, u32x4& a1, u32x4& a2, u32x4& a3) {
  asm volatile(
      "global_load_dwordx4 %0, %4, off sc1\n\t"
      "global_load_dwordx4 %1, %5, off sc1\n\t"
      "global_load_dwordx4 %2, %6, off sc1\n\t"
      "global_load_dwordx4 %3, %7, off sc1\n\t"
      "s_waitcnt vmcnt(0)"
      : "=&v"(a0), "=&v"(a1), "=&v"(a2), "=&v"(a3)
      : "v"(p0), "v"(p1), "v"(p2), "v"(p3)
      : "memory");
}
__device__ __forceinline__ s16x8 as_frag(u32x4 v) {
  union { u32x4 u; s16x8 s; } c; c.u = v; return c.s;
}

__device__ __forceinline__ float dot8_f32(const float* hv, const float* wp, float acc) {
  float4 w0 = *(const float4*)wp;
  float4 w1 = *(const float4*)(wp + 4);
  acc += hv[0] * w0.x; acc += hv[1] * w0.y; acc += hv[2] * w0.z; acc += hv[3] * w0.w;
  acc += hv[4] * w1.x; acc += hv[5] * w1.y; acc += hv[6] * w1.z; acc += hv[7] * w1.w;
  return acc;
}

// ---- diagnostic flood (f32 out) ----
__global__ void floodk(float* out, float val, unsigned long long n) {
  unsigned long long i = (unsigned long long)blockIdx.x * 256 + threadIdx.x;
  if (i < n) out[i] = val;
}

// ---- init: states to feature-major f32 + batch-major bf16; zero flags ----
__global__ void init_state(const float* __restrict__ h0, const float* __restrict__ c0,
                           float* __restrict__ hT, float* __restrict__ cT,
                           u16* __restrict__ hx16, u32* flags) {
  int i = blockIdx.x * 256 + threadIdx.x;   // 0..65535
  int k = i >> 6, b = i & 63;
  float hv = h0[b * ND + k];
  hT[i] = hv;
  cT[i] = c0[b * ND + k];
  hx16[b * ND + k] = f2bf(hv);
  if (i < NBLK * 16) flags[i] = 0u;
}

// ================= persistent fused sequence kernel (MFMA) =================
// 256 blocks x 512 thr. bf16 weights in LDS (XOR-swizzled rows).
// Exchange: packed bf16 [b][k/2] via sc1. mfma_f32_16x16x32_bf16:
//   A frag: lane l -> row l&15, k=(l>>4)*8+j (16B contiguous = 1 sc1 dwordx4)
//   B frag: lane l -> col l&15, same k      (16B contiguous = 1 ds_read_b128)
//   C: col=lane&15, row=(lane>>4)*4+reg  [m89-verified]

__device__ __forceinline__ void fbar(u32* flags, u32 want) {
  asm volatile("s_waitcnt vmcnt(0)" ::: "memory");
  __syncthreads();
  const int tid = threadIdx.x;
  if (tid == 0)
    __hip_atomic_store(flags + (size_t)blockIdx.x * 16, want,
                       __ATOMIC_RELAXED, __HIP_MEMORY_SCOPE_AGENT);
  if (tid < 64) {
    for (;;) {
      int ok = 1;
#pragma unroll
      for (int i = 0; i < 4; ++i) {
        u32 f = __hip_atomic_load(flags + (size_t)(tid * 4 + i) * 16,
                                  __ATOMIC_RELAXED, __HIP_MEMORY_SCOPE_AGENT);
        ok &= (f >= want);
      }
      if (__all(ok)) break;
      __builtin_amdgcn_s_sleep(1);
    }
  }
  __syncthreads();
}

// mog: out cols c0..c0+3 = 2*sig(act.W + b) * mult. rowbase = phase*4 in wAll.
template<bool EMB>
__device__ __forceinline__ void mogP(
    const u32* __restrict__ actU, const u16* wAll, int rowbase, const float* bL,
    const float* __restrict__ emb, const int* __restrict__ tok,
    const u32* __restrict__ multU, u32* __restrict__ outU,
    float* red, float* vals2, float* vals)
{
  const int tid = threadIdx.x;
  const int wv = tid >> 6, lane = tid & 63;
  const int c0 = blockIdx.x * 4;
  const int kb = wv * 128;
  const int lm = lane & 15, lh = lane >> 4;
  const u32* ap = actU + (size_t)lm * 512 + (kb >> 1) + lh * 4;
  const int g = rowbase + lm;                       // B row (LDS), n = lm
  const int swz = (g & 7) << 3;
  f32x4 acc0 = {0.f,0.f,0.f,0.f}, acc1 = acc0, acc2 = acc0, acc3 = acc0;

#pragma unroll
  for (int ks = 0; ks < 4; ++ks) {
    u32x4 a0, a1, a2, a3;
    const u32* p = ap + ks * 16;
    ld_afrag4(p, p + 8192, p + 16384, p + 24576, a0, a1, a2, a3);
    const int e = (kb + ks * 32 + lh * 8) ^ swz;
    s16x8 bf = *(const s16x8*)(wAll + g * 1024 + e);
    acc0 = __builtin_amdgcn_mfma_f32_16x16x32_bf16(as_frag(a0), bf, acc0, 0, 0, 0);
    acc1 = __builtin_amdgcn_mfma_f32_16x16x32_bf16(as_frag(a1), bf, acc1, 0, 0, 0);
    acc2 = __builtin_amdgcn_mfma_f32_16x16x32_bf16(as_frag(a2), bf, acc2, 0, 0, 0);
    acc3 = __builtin_amdgcn_mfma_f32_16x16x32_bf16(as_frag(a3), bf, acc3, 0, 0, 0);
  }
#pragma unroll
  for (int r = 0; r < 4; ++r) {
    red[wv * 1024 + (r     ) * 64 + lane] = acc0[r];
    red[wv * 1024 + (4 + r ) * 64 + lane] = acc1[r];
    red[wv * 1024 + (8 + r ) * 64 + lane] = acc2[r];
    red[wv * 1024 + (12 + r) * 64 + lane] = acc3[r];
  }
  __syncthreads();
  {
    float s0 = 0.f, s1 = 0.f;
#pragma unroll
    for (int w = 0; w < 8; ++w) { s0 += red[w * 1024 + tid]; s1 += red[w * 1024 + 512 + tid]; }
    vals2[tid] = s0; vals2[512 + tid] = s1;
  }
  __syncthreads();

  if (tid < 256) {
    const int c = tid >> 6, b = tid & 63;
    const int i = ((b >> 4) << 2) | (b & 3);
    const int l = (((b >> 2) & 3) << 4) | c;
    float z = vals2[i * 64 + l] + bL[c];
    float g2 = 2.f * sigf(z);
    float m;
    if (EMB) {
      m = emb[(size_t)tok[b] * ND + (c0 + c)];
    } else {
      u32 mu = ld_uc1(multU + (size_t)b * 512 + ((c0 + c) >> 1));
      m = (c & 1) ? bfhi(mu) : bflo(mu);
    }
    vals[c * 64 + b] = g2 * m;
  }
  __syncthreads();

  if (tid < 128) {
    const int cp = tid >> 6, b = tid & 63;
    float lo = vals[(2 * cp) * 64 + b];
    float hi = vals[(2 * cp + 1) * 64 + b];
    u32 pk = (u32)f2bf(lo) | ((u32)f2bf(hi) << 16);
    st_uc1(outU + (size_t)b * 512 + (c0 >> 1) + cp, pk);
  }
}

// gates: rows n = jj*4+g (16 per block). waves 0-3 x-half, 4-7 h-half.
__device__ __forceinline__ void gatesP(
    const u32* __restrict__ xU, const u32* __restrict__ hU,
    const u16* wAll, const float* bG, float& creg,
    float* __restrict__ hHistN, u32* __restrict__ hxU,
    float* red, float* vals2, float* vals)
{
  const int tid = threadIdx.x;
  const int wv = tid >> 6, lane = tid & 63;
  const int j0 = blockIdx.x * 4;
  const int half = wv >> 2, kq = wv & 3;
  const int kb = kq * 256;
  const int lm = lane & 15, lh = lane >> 4;
  const u32* ap = (half ? hU : xU) + (size_t)lm * 512 + (kb >> 1) + lh * 4;
  const int g = 16 + half * 16 + lm;                // global LDS row, n = lm
  const int swz = (g & 7) << 3;
  f32x4 acc0 = {0.f,0.f,0.f,0.f}, acc1 = acc0, acc2 = acc0, acc3 = acc0;

#pragma unroll
  for (int ks = 0; ks < 8; ++ks) {
    u32x4 a0, a1, a2, a3;
    const u32* p = ap + ks * 16;
    ld_afrag4(p, p + 8192, p + 16384, p + 24576, a0, a1, a2, a3);
    const int e = (kb + ks * 32 + lh * 8) ^ swz;
    s16x8 bf = *(const s16x8*)(wAll + g * 1024 + e);
    acc0 = __builtin_amdgcn_mfma_f32_16x16x32_bf16(as_frag(a0), bf, acc0, 0, 0, 0);
    acc1 = __builtin_amdgcn_mfma_f32_16x16x32_bf16(as_frag(a1), bf, acc1, 0, 0, 0);
    acc2 = __builtin_amdgcn_mfma_f32_16x16x32_bf16(as_frag(a2), bf, acc2, 0, 0, 0);
    acc3 = __builtin_amdgcn_mfma_f32_16x16x32_bf16(as_frag(a3), bf, acc3, 0, 0, 0);
  }
#pragma unroll
  for (int r = 0; r < 4; ++r) {
    red[wv * 1024 + (r     ) * 64 + lane] = acc0[r];
    red[wv * 1024 + (4 + r ) * 64 + lane] = acc1[r];
    red[wv * 1024 + (8 + r ) * 64 + lane] = acc2[r];
    red[wv * 1024 + (12 + r) * 64 + lane] = acc3[r];
  }
  __syncthreads();
  {
    float s0 = 0.f, s1 = 0.f;
#pragma unroll
    for (int w = 0; w < 8; ++w) { s0 += red[w * 1024 + tid]; s1 += red[w * 1024 + 512 + tid]; }
    vals2[tid] = s0; vals2[512 + tid] = s1;
  }
  __syncthreads();

  if (tid < 256) {
    const int jj = tid >> 6, b = tid & 63;
    const int i = ((b >> 4) << 2) | (b & 3);
    const int lbase = (((b >> 2) & 3) << 4);
    float pre[4];
#pragma unroll
    for (int gg = 0; gg < 4; ++gg) {
      const int n = jj * 4 + gg;
      pre[gg] = vals2[i * 64 + (lbase | n)] + bG[n];
    }
    float iv = sigf(pre[0]), fv = sigf(pre[1]);
    float gv = tanhf(pre[2]), ov = sigf(pre[3]);
    float cn = fv * creg + iv * gv;
    creg = cn;
    float hn = ov * tanhf(cn);
    hHistN[(size_t)(j0 + jj) * NB + b] = hn;        // f32, decode-only
    vals[jj * 64 + b] = hn;
  }
  __syncthreads();

  if (tid < 128) {
    const int cp = tid >> 6, b = tid & 63;
    float lo = vals[(2 * cp) * 64 + b];
    float hi = vals[(2 * cp + 1) * 64 + b];
    u32 pk = (u32)f2bf(lo) | ((u32)f2bf(hi) << 16);
    st_uc1(hxU + (size_t)b * 512 + (j0 >> 1) + cp, pk);
  }
}

__global__ __launch_bounds__(512) void seq_kernel(
    const int* __restrict__ tokens, const float* __restrict__ emb,
    const float* __restrict__ qw, const float* __restrict__ qb,
    const float* __restrict__ rw, const float* __restrict__ rb,
    const float* __restrict__ wih, const float* __restrict__ whh,
    const float* __restrict__ bih, const float* __restrict__ bhh,
    u32* __restrict__ hxU, u32* __restrict__ xAU, u32* __restrict__ h1U,
    u32* __restrict__ xBU, u32* __restrict__ h3U,
    float* __restrict__ cS, float* __restrict__ hHist, u32* flags)
{
  __shared__ u16 wAll[48 * 1024];        // 96 KB: rows 0-15 mog, 16-47 gates
  __shared__ float red[8 * 1024];        // 32 KB
  __shared__ float vals2[1024];          // 4 KB
  __shared__ float vals[256];
  __shared__ float bMog[4][4];
  __shared__ float bGs[16];

  const int tid = threadIdx.x;
  const int c0 = blockIdx.x * 4;
  const size_t DH = (size_t)ND * ND;
  const size_t SB = (size_t)ND * NB;

  // ---- one-time LDS weight fill (f32 -> bf16 RNE, XOR-swizzled rows) ----
  {
    const float* msrc[4] = {qw, rw, qw + DH, rw + DH};
#pragma unroll
    for (int m = 0; m < 4; ++m)
      for (int c = 0; c < 4; ++c) {
        const int g = m * 4 + c;
        const float* src = msrc[m] + (size_t)(c0 + c) * ND;
        u16* dst = wAll + g * 1024;
        const int swz = (g & 7) << 3;
        for (int k = tid; k < ND; k += 512) dst[k ^ swz] = f2bf(src[k]);
      }
#pragma unroll
    for (int m = 0; m < 2; ++m) {
      const float* W = m ? whh : wih;
      for (int r = 0; r < 16; ++r) {
        const int g = 16 + m * 16 + r;
        const float* src = W + ((size_t)(r & 3) * ND + c0 + (r >> 2)) * ND;
        u16* dst = wAll + g * 1024;
        const int swz = (g & 7) << 3;
        for (int k = tid; k < ND; k += 512) dst[k ^ swz] = f2bf(src[k]);
      }
    }
    if (tid < 16) {
      int p = tid >> 2, c = tid & 3;
      const float* bs = (p == 0) ? qb : (p == 1) ? rb : (p == 2) ? qb + ND : rb + ND;
      bMog[p][c] = bs[c0 + c];
    }
    if (tid >= 16 && tid < 32) {
      int r = tid - 16;
      int jj = r >> 2, g = r & 3;
      bGs[r] = bih[g * ND + c0 + jj] + bhh[g * ND + c0 + jj];
    }
  }
  float creg = 0.f;
  if (tid < 256) creg = cS[(size_t)(c0 + (tid >> 6)) * NB + (tid & 63)];
  __syncthreads();

  u32 want = 0;
  for (int t = 0; t < SEQ_LEN; ++t) {
    const int* tok = tokens + (size_t)t * NB;
    float* hn = hHist + (size_t)(t + 1) * SB;
    mogP<true >(hxU, wAll, 0,  bMog[0], emb, tok, nullptr, xAU, red, vals2, vals); fbar(flags, ++want);
    mogP<false>(xAU, wAll, 4,  bMog[1], nullptr, nullptr, hxU, h1U, red, vals2, vals); fbar(flags, ++want);
    mogP<false>(h1U, wAll, 8,  bMog[2], nullptr, nullptr, xAU, xBU, red, vals2, vals); fbar(flags, ++want);
    mogP<false>(xBU, wAll, 12, bMog[3], nullptr, nullptr, h1U, h3U, red, vals2, vals); fbar(flags, ++want);
    gatesP(xBU, h3U, wAll, bGs, creg, hn, hxU, red, vals2, vals);                      fbar(flags, ++want);
  }
  if (tid < 256) cS[(size_t)(c0 + (tid >> 6)) * NB + (tid & 63)] = creg;
}

// ================= fallback multi-launch kernels (proven) =================

template<bool EMB>
__global__ __launch_bounds__(256) void mog_phase(
    const float* __restrict__ actT, const float* __restrict__ W,
    const float* __restrict__ bias, const float* __restrict__ multT,
    const float* __restrict__ emb, const int* __restrict__ tok,
    float* __restrict__ outT)
{
  const int tid = threadIdx.x;
  const int wv = tid >> 6;
  const int lane = tid & 63;
  const int c0 = blockIdx.x * 4;
  __shared__ float red[4][4][64];

  float acc[4] = {0.f, 0.f, 0.f, 0.f};
  const int kb = wv * 256;
  const float* ap = actT + (size_t)kb * NB + lane;

  for (int k = 0; k < 256; k += 8) {
    float hv[8];
#pragma unroll
    for (int q = 0; q < 8; ++q) hv[q] = ap[(k + q) * NB];
#pragma unroll
    for (int c = 0; c < 4; ++c)
      acc[c] = dot8_f32(hv, W + (size_t)(c0 + c) * ND + kb + k, acc[c]);
  }
#pragma unroll
  for (int c = 0; c < 4; ++c) red[wv][c][lane] = acc[c];
  __syncthreads();

  const int c = tid >> 6, b = tid & 63;
  float z = red[0][c][b] + red[1][c][b] + red[2][c][b] + red[3][c][b];
  z += bias[c0 + c];
  float g = 2.f * sigf(z);
  float m;
  if (EMB) m = emb[(size_t)tok[b] * ND + (c0 + c)];
  else     m = multT[(size_t)(c0 + c) * NB + b];
  outT[(size_t)(c0 + c) * NB + b] = g * m;
}

__global__ __launch_bounds__(256) void lstm_gates2(
    const float* __restrict__ xT, const float* __restrict__ hT,
    const float* __restrict__ Wih, const float* __restrict__ Whh,
    const float* __restrict__ bih, const float* __restrict__ bhh,
    float* __restrict__ cT, float* __restrict__ hOut)
{
  const int tid = threadIdx.x;
  const int wv = tid >> 6, lane = tid & 63;
  const int j0 = blockIdx.x * 2;
  __shared__ float red[4][16][64];
  float acc[16];
#pragma unroll
  for (int i = 0; i < 16; ++i) acc[i] = 0.f;
  const int kb = wv * 256;
  const float* xp = xT + (size_t)kb * NB + lane;
  const float* hp = hT + (size_t)kb * NB + lane;

  for (int k = 0; k < 256; k += 8) {
    float xv[8], hv[8];
#pragma unroll
    for (int q = 0; q < 8; ++q) { xv[q] = xp[(k + q) * NB]; hv[q] = hp[(k + q) * NB]; }
#pragma unroll
    for (int jj = 0; jj < 2; ++jj)
#pragma unroll
      for (int g = 0; g < 4; ++g) {
        const size_t row = (size_t)(g * ND + j0 + jj) * ND + kb + k;
        acc[jj * 8 + g]     = dot8_f32(xv, Wih + row, acc[jj * 8 + g]);
        acc[jj * 8 + 4 + g] = dot8_f32(hv, Whh + row, acc[jj * 8 + 4 + g]);
      }
  }
#pragma unroll
  for (int i = 0; i < 16; ++i) red[wv][i][lane] = acc[i];
  __syncthreads();

  if (tid < 128) {
    const int b = tid & 63, jj = tid >> 6;
    const int j = j0 + jj;
    float pre[4];
#pragma unroll
    for (int g = 0; g < 4; ++g) {
      float s = 0.f;
#pragma unroll
      for (int w = 0; w < 4; ++w) s += red[w][jj * 8 + g][b] + red[w][jj * 8 + 4 + g][b];
      pre[g] = s + bih[g * ND + j] + bhh[g * ND + j];
    }
    float iv = sigf(pre[0]), fv = sigf(pre[1]);
    float gv = tanhf(pre[2]), ov = sigf(pre[3]);
    float cn = fv * cT[(size_t)j * NB + b] + iv * gv;
    float hn = ov * tanhf(cn);
    cT[(size_t)j * NB + b] = cn;
    hOut[(size_t)j * NB + b] = hn;
  }
}

__global__ __launch_bounds__(256) void decode_k(
    const float* __restrict__ hT, const float* __restrict__ W,
    const float* __restrict__ decb, float* __restrict__ out)
{
  const int tid = threadIdx.x;
  const int wv = tid >> 6, lane = tid & 63;
  const int v0 = blockIdx.x * 4;
  __shared__ float red[4][4][64];
  float acc[4] = {0.f, 0.f, 0.f, 0.f};
  const int kb = wv * 256;
  const float* hp = hT + (size_t)kb * NB + lane;

  for (int k = 0; k < 256; k += 8) {
    float hv[8];
#pragma unroll
    for (int q = 0; q < 8; ++q) hv[q] = hp[(k + q) * NB];
#pragma unroll
    for (int c = 0; c < 4; ++c)
      acc[c] = dot8_f32(hv, W + (size_t)(v0 + c) * ND + kb + k, acc[c]);
  }
#pragma unroll
  for (int c = 0; c < 4; ++c) red[wv][c][lane] = acc[c];
  __syncthreads();

  const int c = tid >> 6, b = tid & 63;
  float z = red[0][c][b] + red[1][c][b] + red[2][c][b] + red[3][c][b];
  z += decb[v0 + c];
  out[(size_t)b * NV + v0 + c] = z;
}

// ---- batched decode GEMM over the whole h-history ----
__global__ __launch_bounds__(256) void decode_gemm(
    const float* __restrict__ A,      // [t][k][b]
    const float* __restrict__ Bw,     // [n][k]
    const float* __restrict__ bias,
    float* __restrict__ C)            // [t][b][n]
{
  const int tid = threadIdx.x;
  const int bid = blockIdx.x;
  const int mt = bid & 255;
  const int nt = bid >> 8;
  const int n0 = nt * 64;

  __shared__ float As[2048];
  __shared__ float Bs[2048];

  const int tm = tid >> 4, tn = tid & 15;
  float acc[4][4] = {{0.f}};
  const float* Abase = A + (size_t)mt * (ND * NB);

  for (int k0 = 0; k0 < ND; k0 += 32) {
    __syncthreads();
    {
      const float4* src = (const float4*)(Abase + (size_t)k0 * NB);
      ((float4*)As)[tid] = src[tid];
      ((float4*)As)[tid + 256] = src[tid + 256];
    }
#pragma unroll
    for (int i = 0; i < 2; ++i) {
      int f = tid + i * 256;
      int n = f >> 3;
      int kc = f & 7;
      int gn = n0 + n;
      float4 v = make_float4(0.f, 0.f, 0.f, 0.f);
      if (gn < NV) v = *(const float4*)(Bw + (size_t)gn * ND + k0 + kc * 4);
      int k = kc * 4;
      int n4 = n >> 2, nr = n & 3;
      Bs[(k + 0) * 64 + ((n4 ^ ((k + 0) & 7)) << 2) + nr] = v.x;
      Bs[(k + 1) * 64 + ((n4 ^ ((k + 1) & 7)) << 2) + nr] = v.y;
      Bs[(k + 2) * 64 + ((n4 ^ ((k + 2) & 7)) << 2) + nr] = v.z;
      Bs[(k + 3) * 64 + ((n4 ^ ((k + 3) & 7)) << 2) + nr] = v.w;
    }
    __syncthreads();
#pragma unroll
    for (int kk = 0; kk < 32; ++kk) {
      float a4[4], b4[4];
      *(float4*)a4 = *(const float4*)(As + kk * 64 + tm * 4);
      *(float4*)b4 = *(const float4*)(Bs + kk * 64 + ((tn ^ (kk & 7)) << 2));
#pragma unroll
      for (int i = 0; i < 4; ++i)
#pragma unroll
        for (int j = 0; j < 4; ++j)
          acc[i][j] = fmaf(a4[i], b4[j], acc[i][j]);
    }
  }

  const int nb = n0 + tn * 4;
  float db[4];
#pragma unroll
  for (int j = 0; j < 4; ++j) db[j] = (nb + j < NV) ? bias[nb + j] : 0.f;
  float* Crow = C + (size_t)mt * ((size_t)NB * NV);
#pragma unroll
  for (int i = 0; i < 4; ++i) {
    const int b = tm * 4 + i;
    float* cp = Crow + (size_t)b * NV + nb;
    if (nb + 3 < NV) {
      float4 v;
      v.x = acc[i][0] + db[0]; v.y = acc[i][1] + db[1];
      v.z = acc[i][2] + db[2]; v.w = acc[i][3] + db[3];
      *(float4*)cp = v;
    } else {
#pragma unroll
      for (int j = 0; j < 4; ++j)
        if (nb + j < NV) cp[j] = acc[i][j] + db[j];
    }
  }
}

__global__ void finalize(const float* __restrict__ hT, const float* __restrict__ cT,
                         float* __restrict__ out) {
  int i = blockIdx.x * 256 + threadIdx.x;
  int k = i >> 6, b = i & 63;
  size_t base = (size_t)SEQ_LEN * NB * NV;
  out[base + (size_t)b * ND + k] = hT[i];
  out[base + (size_t)NB * ND + (size_t)b * ND + k] = cT[i];
}

extern "C" void kernel_launch(void* const* d_in, const int* in_sizes, int n_in,
                              void* d_out, int out_size, void* d_ws, size_t ws_size,
                              hipStream_t stream)
{
  float* out = (float*)d_out;
  const unsigned long long expect_out = (unsigned long long)SEQ_LEN * NB * NV + 2ull * NB * ND;

  auto flood = [&](float v) {
    unsigned long long n = (unsigned long long)out_size;
    unsigned int g = (unsigned int)((n + 255) / 256);
    floodk<<<g, 256, 0, stream>>>(out, v, n);
  };
  const int expect_sz[14] = {
    SEQ_LEN * NB, NV * ND, 2 * ND * ND, 2 * ND, 2 * ND * ND, 2 * ND,
    4 * ND * ND, 4 * ND * ND, 4 * ND, 4 * ND, NV * ND, NV, NB * ND, NB * ND };
  if (n_in != 14) { flood(1000.f); return; }
  for (int i = 0; i < 14; ++i)
    if (in_sizes[i] != expect_sz[i]) { flood(1100.f + 100.f * i); return; }
  if ((unsigned long long)out_size != expect_out) { flood(2500.f); return; }

  float* ws = (float*)d_ws;
  const size_t SB = (size_t)ND * NB;   // 65536
  if (ws_size < 7 * SB * sizeof(float)) { flood(2600.f); return; }

  const int*   tokens = (const int*)d_in[0];
  const float* emb  = (const float*)d_in[1];
  const float* qw   = (const float*)d_in[2];
  const float* qb   = (const float*)d_in[3];
  const float* rw   = (const float*)d_in[4];
  const float* rb   = (const float*)d_in[5];
  const float* wih  = (const float*)d_in[6];
  const float* whh  = (const float*)d_in[7];
  const float* bih  = (const float*)d_in[8];
  const float* bhh  = (const float*)d_in[9];
  const float* decw = (const float*)d_in[10];
  const float* decb = (const float*)d_in[11];
  const float* h0   = (const float*)d_in[12];
  const float* c0   = (const float*)d_in[13];

  // big layout: cS | hHist[257] | 5 bf16 exchange buffers | flags
  float* cS    = ws;
  float* hHist = ws + SB;
  u32*   ex    = (u32*)(ws + SB + (size_t)(SEQ_LEN + 1) * SB);
  const size_t EXB = 64 * 512;         // u32 per exchange buffer
  u32* hxU = ex + 0 * EXB;
  u32* xAU = ex + 1 * EXB;
  u32* h1U = ex + 2 * EXB;
  u32* xBU = ex + 3 * EXB;
  u32* h3U = ex + 4 * EXB;
  u32* flags = ex + 5 * EXB;

  const size_t DH = (size_t)ND * ND;
  const size_t need = ((size_t)(1 + SEQ_LEN + 1) * SB) * sizeof(float)
                    + (5 * EXB + NBLK * 16) * sizeof(u32);
  const bool big = ws_size >= need;

  if (big) {
    init_state<<<256, 256, 0, stream>>>(h0, c0, hHist, cS, (u16*)hxU, flags);
    seq_kernel<<<NBLK, 512, 0, stream>>>(tokens, emb, qw, qb, rw, rb,
                                         wih, whh, bih, bhh,
                                         hxU, xAU, h1U, xBU, h3U,
                                         cS, hHist, flags);
    decode_gemm<<<157 * 256, 256, 0, stream>>>(hHist + SB, decw, decb, out);
    finalize<<<256, 256, 0, stream>>>(hHist + (size_t)SEQ_LEN * SB, cS, out);
  } else {
    // fallback: proven multi-launch path
    float* xA = ws + 0 * SB;
    float* xB = ws + 1 * SB;
    float* h1 = ws + 2 * SB;
    float* h3 = ws + 3 * SB;
    float* cSf = ws + 4 * SB;
    float* hA = ws + 5 * SB;
    float* hB = ws + 6 * SB;
    u32* fdummy = (u32*)(ws + 6 * SB);
    init_state<<<256, 256, 0, stream>>>(h0, c0, hA, cSf, (u16*)hB, fdummy);
    float* hc = hA;
    float* hn = hB;
    for (int t = 0; t < SEQ_LEN; ++t) {
      const int* tk = tokens + (size_t)t * NB;
      mog_phase<true ><<<256, 256, 0, stream>>>(hc, qw, qb, nullptr, emb, tk, xA);
      mog_phase<false><<<256, 256, 0, stream>>>(xA, rw, rb, hc, nullptr, nullptr, h1);
      mog_phase<false><<<256, 256, 0, stream>>>(h1, qw + DH, qb + ND, xA, nullptr, nullptr, xB);
      mog_phase<false><<<256, 256, 0, stream>>>(xB, rw + DH, rb + ND, h1, nullptr, nullptr, h3);
      lstm_gates2<<<512, 256, 0, stream>>>(xB, h3, wih, whh, bih, bhh, cSf, hn);
      decode_k<<<2500, 256, 0, stream>>>(hn, decw, decb, out + (size_t)t * NB * NV);
      float* tmp = hc; hc = hn; hn = tmp;
    }
    finalize<<<256, 256, 0, stream>>>(hc, cSf, out);
  }
}